// Round 9
// baseline (528.076 us; speedup 1.0000x reference)
//
#include <hip/hip_runtime.h>
#include <math.h>

// ---------------------------------------------------------------------------
// MemTransformerLM (Transformer-XL layer) — round 15.
// attn: r12 form + s_setprio(1) around the two MFMA clusters (T5, proven
//   +4-7% on attn per catalog m191).
// QKV split: KV-GEMM (8192x2048, grid 256 = one exact 1-block/CU round) +
//   Q-GEMM over w-rows only (4096x1024, 64 blocks) — eliminates the 8.6
//   GFLOP of Q computed for mems rows and then discarded, and removes the
//   384-block 2-round tail quantization.
// mgemm2: dropped the hazard-free mid-tile barrier (was pure rhythm).
// ---------------------------------------------------------------------------

#define QLEN 1024
#define BSZ  4
#define DMODEL 1024
#define NHEAD 16
#define DHEAD 64
#define DINNER 4096
#define MEMLEN 1024
#define KLEN 2048

typedef __attribute__((ext_vector_type(8))) short short8;
typedef __attribute__((ext_vector_type(4))) short short4_t;
typedef __attribute__((ext_vector_type(4))) float f32x4;

__device__ __forceinline__ unsigned short f2bf(float x) {
  union { float f; unsigned u; } cv; cv.f = x;
  const unsigned u = cv.u;
  return (unsigned short)((u + 0x7FFFu + ((u >> 16) & 1u)) >> 16);
}
__device__ __forceinline__ float bf2f(unsigned short b) {
  union { unsigned u; float f; } cv; cv.u = ((unsigned)b) << 16;
  return cv.f;
}

__device__ __forceinline__ void gload16(const void* g, void* l) {
  __builtin_amdgcn_global_load_lds(
      (const __attribute__((address_space(1))) unsigned int*)g,
      (__attribute__((address_space(3))) unsigned int*)l, 16, 0, 0);
}

__device__ __forceinline__ int chidx(int row, int kc) {
  return row * 4 + (kc ^ ((row >> 1) & 3));
}

// ---------------------------------------------------------------------------
// mgemm2: C[M,N] = A[M,K] @ Bt[N,K]^T, 256x256 tile, BK=32, 512 threads.
// Depth-2 pipeline, 96KB LDS (3 bufs), vmcnt(8/4/0) ladder. 2 barriers/tile.
// MODE 0: KV (N=2048, sec 0=K 1=V). MODE 1: Q-only (A = w-rows of Xcat).
// MODE 3: FFN up + bias + relu. LDS-staged vectorized C-store.
// ---------------------------------------------------------------------------
template<int MODE>
__global__ __launch_bounds__(512) void mgemm2(
    const unsigned short* __restrict__ A, const unsigned short* __restrict__ Bt,
    unsigned short* __restrict__ Cb, const float* __restrict__ aux,
    unsigned short* __restrict__ oK, unsigned short* __restrict__ oV,
    int Kdim, int N)
{
  __shared__ __align__(16) char smem[98304];

  const int tid = threadIdx.x;
  const int lane = tid & 63, wv = tid >> 6;
  const int wr = wv >> 2, wc = wv & 3;
  const int quad = lane >> 4, l15 = lane & 15;

  const int gx = (int)gridDim.x;
  const int nwg = gx * (int)gridDim.y;
  const int flat = (int)blockIdx.y * gx + (int)blockIdx.x;
  const int swz = (flat & 7) * (nwg >> 3) + (flat >> 3);
  const int m0 = (swz / gx) * 256, n0 = (swz % gx) * 256;

  const int srow = tid >> 2;
  const int skc = (tid & 3) ^ ((srow >> 1) & 3);
  const unsigned short* pA0 = A + (size_t)(m0 + srow) * Kdim + skc * 8;
  const unsigned short* pA1 = A + (size_t)(m0 + 128 + srow) * Kdim + skc * 8;
  const unsigned short* pB0 = Bt + (size_t)(n0 + srow) * Kdim + skc * 8;
  const unsigned short* pB1 = Bt + (size_t)(n0 + 128 + srow) * Kdim + skc * 8;
  const int wb = (tid & 448) * 16;          // wave-uniform LDS base

  const int cch = (quad ^ ((l15 >> 1) & 3)) * 16;
  const int aoffb = wr * 8192 + l15 * 64 + cch;                      // +i*1024
  const int boffb = (wc >> 1) * 8192 + ((wc & 1) * 64 + l15) * 64 + cch;

  f32x4 acc[8][4] = {};

  const int nkt = Kdim >> 5;
  // prologue: stage kt=0 -> buf0, kt=1 -> buf1 (8 loads outstanding)
  gload16(pA0, smem + wb);
  gload16(pA1, smem + 8192 + wb);
  gload16(pB0, smem + 49152 + wb);
  gload16(pB1, smem + 57344 + wb);
  pA0 += 32; pA1 += 32; pB0 += 32; pB1 += 32;
  gload16(pA0, smem + 16384 + wb);
  gload16(pA1, smem + 24576 + wb);
  gload16(pB0, smem + 65536 + wb);
  gload16(pB1, smem + 73728 + wb);
  pA0 += 32; pA1 += 32; pB0 += 32; pB1 += 32;

  int rbuf = 0;
  for (int kt = 0; kt < nkt; ++kt) {
    if (kt + 2 < nkt) {
      int wb3 = rbuf + 2; if (wb3 >= 3) wb3 -= 3;
      const int ab = wb3 * 16384, bb = 49152 + wb3 * 16384;
      gload16(pA0, smem + ab + wb);
      gload16(pA1, smem + ab + 8192 + wb);
      gload16(pB0, smem + bb + wb);
      gload16(pB1, smem + bb + 8192 + wb);
      pA0 += 32; pA1 += 32; pB0 += 32; pB1 += 32;
      asm volatile("s_waitcnt vmcnt(8)" ::: "memory");
    } else if (kt + 1 < nkt) {
      asm volatile("s_waitcnt vmcnt(4)" ::: "memory");
    } else {
      asm volatile("s_waitcnt vmcnt(0)" ::: "memory");
    }
    __builtin_amdgcn_s_barrier();            // A: buf rbuf staged & visible

    const char* const abuf = smem + rbuf * 16384;
    const char* const bbuf = smem + 49152 + rbuf * 16384;

    // ---- phase 0: B all + A rows 0..63 ----
    short8 bfr[4], af[4];
#pragma unroll
    for (int j = 0; j < 4; ++j)
      bfr[j] = *(const short8*)(bbuf + boffb + j * 1024);
#pragma unroll
    for (int i = 0; i < 4; ++i)
      af[i] = *(const short8*)(abuf + aoffb + i * 1024);
    __builtin_amdgcn_s_setprio(1);
#pragma unroll
    for (int i = 0; i < 4; ++i)
#pragma unroll
      for (int j = 0; j < 4; ++j)
        acc[i][j] = __builtin_amdgcn_mfma_f32_16x16x32_bf16(
            af[i], bfr[j], acc[i][j], 0, 0, 0);
    __builtin_amdgcn_s_setprio(0);

    // ---- phase 1: A rows 64..127 (same staged buffer; no barrier needed) ----
#pragma unroll
    for (int i = 0; i < 4; ++i)
      af[i] = *(const short8*)(abuf + aoffb + (i + 4) * 1024);
    __builtin_amdgcn_s_setprio(1);
#pragma unroll
    for (int i = 0; i < 4; ++i)
#pragma unroll
      for (int j = 0; j < 4; ++j)
        acc[i + 4][j] = __builtin_amdgcn_mfma_f32_16x16x32_bf16(
            af[i], bfr[j], acc[i + 4][j], 0, 0, 0);
    __builtin_amdgcn_s_setprio(0);
    asm volatile("s_waitcnt lgkmcnt(0)" ::: "memory");
    __builtin_amdgcn_s_barrier();            // E: all reads of buf rbuf done
    rbuf += 1; if (rbuf == 3) rbuf = 0;
  }

  // ---- epilogue: LDS-staged vectorized C-store ----
  const int cbw = n0 + wc * 64;              // wave-uniform col base
  float bias[4];
  if constexpr (MODE == 3) {
#pragma unroll
    for (int j = 0; j < 4; ++j) bias[j] = aux[cbw + j * 16 + l15];
  }
  unsigned short* const eb = (unsigned short*)(smem + wv * 8192);
  for (int half = 0; half < 2; ++half) {
#pragma unroll
    for (int ii = 0; ii < 4; ++ii) {
#pragma unroll
      for (int r = 0; r < 4; ++r) {
        const int lr = ii * 16 + quad * 4 + r;
#pragma unroll
        for (int j = 0; j < 4; ++j) {
          float v = acc[half * 4 + ii][j][r];
          if constexpr (MODE == 3) v = fmaxf(v + bias[j], 0.f);
          const int slot = (j * 2 + (l15 >> 3)) ^ (lr & 7);
          eb[lr * 64 + slot * 8 + (l15 & 7)] = f2bf(v);
        }
      }
    }
    const int grow = m0 + wr * 128 + half * 64 + lane;
    short8 row[8];
#pragma unroll
    for (int g = 0; g < 8; ++g)
      row[g] = *(const short8*)(eb + lane * 64 + ((g ^ (lane & 7)) * 8));
    if constexpr (MODE == 0) {               // KV: sec 0=K, 1=V
      const int kkg = grow >> 2, b2 = grow & 3;
      const int sec = cbw >> 10, hn = (cbw >> 6) & 15;
      unsigned short* dst = (sec == 0)
          ? oK + ((size_t)(b2 * NHEAD + hn) * KLEN + kkg) * DHEAD
          : oV + ((size_t)(b2 * NHEAD + hn) * KLEN + kkg) * DHEAD;
#pragma unroll
      for (int g = 0; g < 8; ++g) *(short8*)(dst + g * 8) = row[g];
    } else if constexpr (MODE == 1) {        // Q (A rows are cat rows 4096+)
      const int qr = grow >> 2, b2 = grow & 3;
      const int hn = (cbw >> 6) & 15;
      unsigned short* dst =
          Cb + ((size_t)(b2 * NHEAD + hn) * QLEN + qr) * DHEAD;
#pragma unroll
      for (int g = 0; g < 8; ++g) *(short8*)(dst + g * 8) = row[g];
    } else {
      unsigned short* dst = Cb + (size_t)grow * N + cbw;
#pragma unroll
      for (int g = 0; g < 8; ++g) *(short8*)(dst + g * 8) = row[g];
    }
  }
}

// ---------------------------------------------------------------------------
// bf16 MFMA GEMM: 128xTN tile, BK=32, 4 waves, depth-2 (3 bufs). (r12 form)
// ---------------------------------------------------------------------------
template<int MODE, int TN>
__global__ __launch_bounds__(256) void mgemm(
    const unsigned short* __restrict__ A, const unsigned short* __restrict__ Bt,
    float* __restrict__ C, unsigned short* __restrict__ Cb,
    const float* __restrict__ aux, const float* __restrict__ res,
    int Kdim, int N)
{
  constexpr int BUF = 8192 + TN * 64;          // bytes per stage buffer
  __shared__ __align__(16) char smem[3 * BUF];

  const int tid = threadIdx.x;
  const int lane = tid & 63, wv = tid >> 6;

  const int gx = (int)gridDim.x;
  const int nwg = gx * (int)gridDim.y;
  const int flat = (int)blockIdx.y * gx + (int)blockIdx.x;
  const int swz = (flat & 7) * (nwg >> 3) + (flat >> 3);
  const int m0 = (swz / gx) * 128, n0 = (swz % gx) * TN;

  const unsigned short *gA0, *gA1, *gB0;
  {
    int c = tid, m = c >> 2, kc = (c & 3) ^ ((m >> 1) & 3);
    gA0 = A + (size_t)(m0 + m) * Kdim + kc * 8;
    c = 256 + tid; m = c >> 2; kc = (c & 3) ^ ((m >> 1) & 3);
    gA1 = A + (size_t)(m0 + m) * Kdim + kc * 8;
    c = tid; int nn = c >> 2; kc = (c & 3) ^ ((nn >> 1) & 3);
    gB0 = Bt + (size_t)(n0 + nn) * Kdim + kc * 8;
  }
  const int wvoff = (tid & 192) * 16;

  const int fr = lane & 15, kq = lane >> 4;
  constexpr int NJ = TN / 32;
  int aoff[4], boff[NJ];
#pragma unroll
  for (int t = 0; t < 4; ++t) {
    const int ra = (wv & 1) * 64 + t * 16 + fr;
    aoff[t] = chidx(ra, kq) * 16;
  }
#pragma unroll
  for (int t = 0; t < NJ; ++t) {
    const int rb = (wv >> 1) * (TN / 2) + t * 16 + fr;
    boff[t] = 8192 + chidx(rb, kq) * 16;
  }

  f32x4 acc[4][NJ] = {};

  // prologue: stage step 0 -> buf0, step 1 -> buf1 (6 loads outstanding)
  {
    char* const b0 = smem + wvoff;
    gload16(gA0, b0);
    gload16(gA1, b0 + 4096);
    gload16(gB0, b0 + 8192);
    gA0 += 32; gA1 += 32; gB0 += 32;
    char* const b1 = smem + BUF + wvoff;
    gload16(gA0, b1);
    gload16(gA1, b1 + 4096);
    gload16(gB0, b1 + 8192);
    gA0 += 32; gA1 += 32; gB0 += 32;
  }

  int rbuf = 0;
  for (int k0 = 0; k0 < Kdim; k0 += 32) {
    if (k0 + 64 < Kdim) {
      int wb3 = rbuf + 2; if (wb3 >= 3) wb3 -= 3;
      char* const nb = smem + wb3 * BUF + wvoff;
      gload16(gA0, nb);
      gload16(gA1, nb + 4096);
      gload16(gB0, nb + 8192);
      gA0 += 32; gA1 += 32; gB0 += 32;
      asm volatile("s_waitcnt vmcnt(6)" ::: "memory");
    } else if (k0 + 32 < Kdim) {
      asm volatile("s_waitcnt vmcnt(3)" ::: "memory");
    } else {
      asm volatile("s_waitcnt vmcnt(0)" ::: "memory");
    }
    __builtin_amdgcn_s_barrier();          // buffer `rbuf` fully staged

    const char* const cb = smem + rbuf * BUF;
    short8 af[4], bfr[NJ];
#pragma unroll
    for (int t = 0; t < 4; ++t) af[t] = *(const short8*)(cb + aoff[t]);
#pragma unroll
    for (int t = 0; t < NJ; ++t) bfr[t] = *(const short8*)(cb + boff[t]);
#pragma unroll
    for (int i = 0; i < 4; ++i)
#pragma unroll
      for (int j = 0; j < NJ; ++j)
        acc[i][j] = __builtin_amdgcn_mfma_f32_16x16x32_bf16(
            af[i], bfr[j], acc[i][j], 0, 0, 0);

    asm volatile("s_waitcnt lgkmcnt(0)" ::: "memory");
    __builtin_amdgcn_s_barrier();          // all reads of `rbuf` done
    rbuf += 1; if (rbuf == 3) rbuf = 0;
  }

  const int rbase = m0 + (wv & 1) * 64 + (lane >> 4) * 4;
  const int cbase = n0 + (wv >> 1) * (TN / 2) + (lane & 15);
#pragma unroll
  for (int i = 0; i < 4; ++i) {
#pragma unroll
    for (int r = 0; r < 4; ++r) {
      const int grow = rbase + i * 16 + r;
#pragma unroll
      for (int j = 0; j < NJ; ++j) {
        const int gcol = cbase + j * 16;
        const float v = acc[i][j][r];
        if constexpr (MODE == 1) {
          const int hn = gcol >> 6, d = gcol & 63;
          Cb[((size_t)hn * KLEN + grow) * DHEAD + d] = f2bf(v);
        } else if constexpr (MODE == 2) {
          C[(size_t)grow * N + gcol] = v + res[(size_t)grow * N + gcol];
        } else {
          C[(size_t)grow * N + gcol] = v + aux[gcol] + res[(size_t)grow * N + gcol];
        }
      }
    }
  }
}

// ---------------------------------------------------------------------------
// Vh [bn][j][d] bf16 -> Vt [bn][d][j] bf16.
// ---------------------------------------------------------------------------
__global__ __launch_bounds__(256) void transpose_v(
    const unsigned short* __restrict__ Vh, unsigned short* __restrict__ Vt)
{
  __shared__ unsigned short t[64 * 80];
  const int j0 = (int)blockIdx.x * 64;
  const int bn = (int)blockIdx.y;
  const int tid = threadIdx.x;
#pragma unroll
  for (int it = 0; it < 2; ++it) {
    const int f = it * 256 + tid;
    const int j = f >> 3, d8 = (f & 7) * 8;
    const short8 v = *(const short8*)(Vh + ((size_t)bn * KLEN + j0 + j) * DHEAD + d8);
    *(short8*)(t + j * 80 + d8) = v;
  }
  __syncthreads();
  const int d = tid >> 2, jseg = (tid & 3) * 16;
  short8 o0, o1;
#pragma unroll
  for (int e = 0; e < 8; ++e) o0[e] = (short)t[(jseg + e) * 80 + d];
#pragma unroll
  for (int e = 0; e < 8; ++e) o1[e] = (short)t[(jseg + 8 + e) * 80 + d];
  unsigned short* op = Vt + ((size_t)bn * DHEAD + d) * KLEN + j0 + jseg;
  *(short8*)op = o0;
  *(short8*)(op + 8) = o1;
}

// ---------------------------------------------------------------------------
// merged input casts: mems|w -> Xcat, r -> Rb16. grid 5120.
// ---------------------------------------------------------------------------
__global__ __launch_bounds__(256) void cast_all(
    const float* __restrict__ mems, const float* __restrict__ w,
    const float* __restrict__ r, unsigned short* __restrict__ Xcat,
    unsigned short* __restrict__ Rb16)
{
  const size_t i = ((size_t)blockIdx.x * 256 + threadIdx.x) * 8;
  const float* src;
  unsigned short* dst;
  if (i < 4194304)       { src = mems + i;          dst = Xcat + i; }
  else if (i < 8388608)  { src = w + (i - 4194304); dst = Xcat + i; }
  else                   { src = r + (i - 8388608); dst = Rb16 + (i - 8388608); }
  const float4 x = *(const float4*)src;
  const float4 y = *(const float4*)(src + 4);
  short8 v;
  v[0] = (short)f2bf(x.x); v[1] = (short)f2bf(x.y);
  v[2] = (short)f2bf(x.z); v[3] = (short)f2bf(x.w);
  v[4] = (short)f2bf(y.x); v[5] = (short)f2bf(y.y);
  v[6] = (short)f2bf(y.z); v[7] = (short)f2bf(y.w);
  *(short8*)dst = v;
}

// ---------------------------------------------------------------------------
// merged weight transposes: fp32 [R][C] -> bf16 [C][R], 5 weights. grid 3328.
// ---------------------------------------------------------------------------
__global__ __launch_bounds__(256) void transpose_all(
    const float* __restrict__ qkv_w, const float* __restrict__ r_net_w,
    const float* __restrict__ o_w, const float* __restrict__ ff_w1,
    const float* __restrict__ ff_w2,
    unsigned short* __restrict__ Wqkv, unsigned short* __restrict__ Wr,
    unsigned short* __restrict__ Wo, unsigned short* __restrict__ W1,
    unsigned short* __restrict__ W2)
{
  const int bid = (int)blockIdx.x;
  const float* in; unsigned short* out; int R, C, xt, loc;
  if (bid < 768)        { in = qkv_w;   out = Wqkv; R = 1024; C = 3072; xt = 48; loc = bid; }
  else if (bid < 1024)  { in = r_net_w; out = Wr;   R = 1024; C = 1024; xt = 16; loc = bid - 768; }
  else if (bid < 1280)  { in = o_w;     out = Wo;   R = 1024; C = 1024; xt = 16; loc = bid - 1024; }
  else if (bid < 2304)  { in = ff_w1;   out = W1;   R = 1024; C = 4096; xt = 64; loc = bid - 1280; }
  else                  { in = ff_w2;   out = W2;   R = 4096; C = 1024; xt = 16; loc = bid - 2304; }
  const int c0 = (loc % xt) * 64, r0 = (loc / xt) * 64;

  __shared__ float t[64][65];
  const int tid = threadIdx.x;
  const int rr = tid >> 4, cc = (tid & 15) * 4;
#pragma unroll
  for (int it = 0; it < 4; ++it) {
    const int rw = rr + it * 16;
    const float4 v = *(const float4*)(in + (size_t)(r0 + rw) * C + c0 + cc);
    t[rw][cc] = v.x; t[rw][cc + 1] = v.y; t[rw][cc + 2] = v.z; t[rw][cc + 3] = v.w;
  }
  __syncthreads();
  const int oc = tid >> 2, ob = (tid & 3) * 16;
#pragma unroll
  for (int j4 = 0; j4 < 4; ++j4) {
    short4_t o;
#pragma unroll
    for (int j = 0; j < 4; ++j) o[j] = (short)f2bf(t[ob + j4 * 4 + j][oc]);
    *(short4_t*)(out + (size_t)(c0 + oc) * R + r0 + ob + j4 * 4) = o;
  }
}

// ---------------------------------------------------------------------------
// MFMA flash relative attention (r12 form + setprio around MFMA clusters).
// Block = 4 waves; i-tile 64; j-split 2. grid 2048 flattened + XCD swizzle.
// LDS 64KB: K dbuf 2x8K @0 | V dbuf 2x8K @16K | R-ring 192 rows (24K) @32K |
//           Ps 8K @57344 (wave-private).
// ---------------------------------------------------------------------------
__global__ __launch_bounds__(256, 2) void attn_mfma(
    const unsigned short* __restrict__ Qh, const unsigned short* __restrict__ Kh,
    const unsigned short* __restrict__ Vt, const unsigned short* __restrict__ Rk,
    const float* __restrict__ rwb, const float* __restrict__ rrb,
    float* __restrict__ Opart0, float* __restrict__ Opart1,
    float* __restrict__ den0, float* __restrict__ den1)
{
  __shared__ __align__(16) char smem[65536];

  const int tid = threadIdx.x;
  const int lane = tid & 63, wv = tid >> 6;
  const int quad = lane >> 4, l15 = lane & 15;

  const int bid0 = (int)blockIdx.y * 32 + (int)blockIdx.x;
  const int slot = bid0 >> 3;
  const int bn = (bid0 & 7) * 8 + (slot >> 5);
  const int inner = slot & 31;
  const int it = inner >> 1, sp = inner & 1;
  const int i0 = it * 64;
  const int n = bn & 15;

  const int nch = 17 + it;
  const int h = (nch + 1) >> 1;
  const int lo = sp ? h : 0, hi = sp ? nch : h;

  const unsigned short* __restrict__ Qb = Qh + (size_t)bn * QLEN * DHEAD;
  const unsigned short* __restrict__ Kb = Kh + (size_t)bn * KLEN * DHEAD;
  const unsigned short* __restrict__ Vb = Vt + (size_t)bn * DHEAD * KLEN;
  const unsigned short* __restrict__ Rb = Rk + (size_t)n * KLEN * DHEAD;

  // persistent Q fragments with biases folded
  short8 qk[2], qr[2];
  {
    const int qrow = i0 + wv * 16 + l15;
    const unsigned short* qp = Qb + (size_t)qrow * DHEAD + quad * 8;
    const float* wp = rwb + n * DHEAD + quad * 8;
    const float* rp = rrb + n * DHEAD + quad * 8;
#pragma unroll
    for (int ks = 0; ks < 2; ++ks) {
      const short8 q8 = *(const short8*)(qp + ks * 32);
#pragma unroll
      for (int e = 0; e < 8; ++e) {
        const float qv = bf2f((unsigned short)q8[e]);
        qk[ks][e] = (short)f2bf(qv + wp[ks * 32 + e]);
        qr[ks][e] = (short)f2bf(qv + rp[ks * 32 + e]);
      }
    }
  }

  // bpermute lane maps + selectors (per register r)
  int srcl[4];
  bool condE[4];
#pragma unroll
  for (int r = 0; r < 4; ++r) {
    const int E = l15 - quad * 4 - r + 15;           // in [0,30]
    srcl[r] = (lane & 48) | (E & 15);
    condE[r] = (E >= 16);
  }

  f32x4 O[4] = {};
  float rden[4] = {0.f, 0.f, 0.f, 0.f};
  const int wvoff = (tid & 192) * 16;

  // ---- prologue: stage chunk `lo` into buffer 0 + full 128-row R window ----
  {
    const int j0 = lo * 64;
    const int g64 = lo - it + 15;                    // window start / 64
    const int rb3 = (g64 % 3) * 64;                  // ring phys base row
#pragma unroll
    for (int t2 = 0; t2 < 2; ++t2) {
      const int s = t2 * 256 + tid;
      const int row = s >> 3, kc = (s & 7) ^ (row & 7);
      gload16(Kb + (((size_t)(j0 + row)) << 6) + kc * 8,
              smem + t2 * 4096 + wvoff);
    }
#pragma unroll
    for (int t2 = 0; t2 < 2; ++t2) {
      const int s = t2 * 256 + tid;
      const int row = s >> 3, kc = (s & 7) ^ (row & 7);
      gload16(Vb + (((size_t)row) << 11) + j0 + kc * 8,
              smem + 16384 + t2 * 4096 + wvoff);
    }
    const int gw = j0 - i0 + 960;
#pragma unroll
    for (int t2 = 0; t2 < 4; ++t2) {
      const int rr = t2 * 32 + (tid >> 3);
      const int gr = gw + rr;
      const int kc = (tid & 7) ^ (rr & 7);
      int pb = rb3 + t2 * 32; if (pb >= 192) pb -= 192;
      gload16(Rb + (((size_t)gr) << 6) + kc * 8,
              smem + 32768 + pb * 128 + wvoff);
    }
  }

  int cur = 0;
  for (int ch = lo; ch < hi; ++ch) {
    const int j0 = ch * 64;
    const int g64 = ch - it + 15;
    const int rb3 = (g64 % 3) * 64;
    const int gw = j0 - i0 + 960;

    asm volatile("s_waitcnt lgkmcnt(0)" ::: "memory");
    __builtin_amdgcn_s_barrier();                    // A: prior reads done

    if (ch + 1 < hi) {
      // prefetch chunk ch+1: K,V into buffer cur^1; R rel rows [128,192)
      const int nb = cur ^ 1;
      const int j0n = j0 + 64;
#pragma unroll
      for (int t2 = 0; t2 < 2; ++t2) {
        const int s = t2 * 256 + tid;
        const int row = s >> 3, kc = (s & 7) ^ (row & 7);
        gload16(Kb + (((size_t)(j0n + row)) << 6) + kc * 8,
                smem + nb * 8192 + t2 * 4096 + wvoff);
      }
#pragma unroll
      for (int t2 = 0; t2 < 2; ++t2) {
        const int s = t2 * 256 + tid;
        const int row = s >> 3, kc = (s & 7) ^ (row & 7);
        gload16(Vb + (((size_t)row) << 11) + j0n + kc * 8,
                smem + 16384 + nb * 8192 + t2 * 4096 + wvoff);
      }
#pragma unroll
      for (int t2 = 0; t2 < 2; ++t2) {
        const int rr = t2 * 32 + (tid >> 3);
        const int gr = gw + 128 + rr;                // pad in Rk covers <=2111
        const int kc = (tid & 7) ^ (rr & 7);
        int pb = rb3 + 128 + t2 * 32; if (pb >= 192) pb -= 192;
        gload16(Rb + (((size_t)gr) << 6) + kc * 8,
                smem + 32768 + pb * 128 + wvoff);
      }
      asm volatile("s_waitcnt vmcnt(6)" ::: "memory");   // ch's loads landed
    } else {
      asm volatile("s_waitcnt vmcnt(0)" ::: "memory");
    }
    __builtin_amdgcn_s_barrier();                    // B: chunk ch visible

    const char* const kbase = smem + cur * 8192;
    const char* const vbase = smem + 16384 + cur * 8192;

    // ---- S_K = (q+rwb)·k  +  U = (q+rrb)·r band (setprio cluster) ----
    f32x4 sk[4];
    __builtin_amdgcn_s_setprio(1);
#pragma unroll
    for (int jt = 0; jt < 4; ++jt) {
      f32x4 a = {0.f, 0.f, 0.f, 0.f};
#pragma unroll
      for (int ks = 0; ks < 2; ++ks) {
        const int frr = jt * 16 + l15;
        const int c = (ks * 4 + quad) ^ (l15 & 7);
        const short8 kf = *(const short8*)(kbase + (frr * 8 + c) * 16);
        a = __builtin_amdgcn_mfma_f32_16x16x32_bf16(qk[ks], kf, a, 0, 0, 0);
      }
      sk[jt] = a;
    }
    f32x4 uu[5];
#pragma unroll
    for (int s = 0; s < 5; ++s) {
      f32x4 a = {0.f, 0.f, 0.f, 0.f};
      int frr = rb3 + (3 - wv + s) * 16 + l15;       // phys ring row
      if (frr >= 192) frr -= 192;
#pragma unroll
      for (int ks = 0; ks < 2; ++ks) {
        const int c = (ks * 4 + quad) ^ (l15 & 7);
        const short8 rf = *(const short8*)(smem + 32768 + (frr * 8 + c) * 16);
        a = __builtin_amdgcn_mfma_f32_16x16x32_bf16(qr[ks], rf, a, 0, 0, 0);
      }
      uu[s] = a;
    }
    __builtin_amdgcn_s_setprio(0);

    // ---- band rotate via bpermute: rot[s][r] = uu[s][r] from lane srcl[r] ----
    float rot[5][4];
#pragma unroll
    for (int s = 0; s < 5; ++s)
#pragma unroll
      for (int r = 0; r < 4; ++r)
        rot[s][r] = __shfl(uu[s][r], srcl[r], 64);

    // ---- P = exp((S_K + U)/8), masked (branchless); Ps wave-private ----
    unsigned short* const Ps = (unsigned short*)(smem + 57344);
#pragma unroll
    for (int jt = 0; jt < 4; ++jt) {
      const int jl = jt * 16 + l15;
#pragma unroll
      for (int r = 0; r < 4; ++r) {
        const int il = wv * 16 + quad * 4 + r;
        const int dj = (j0 + jl) - (i0 + il);
        const float uv = condE[r] ? rot[jt + 1][r] : rot[jt][r];
        const float sv = (sk[jt][r] + uv) * 0.125f;
        const float p = (dj <= 1024) ? __expf(sv) : 0.f;
        rden[r] += p;
        Ps[(il * 8 + ((jl >> 3) ^ (il & 7))) * 8 + (jl & 7)] = f2bf(p);
      }
    }

    // ---- O += P @ V (wave-private P strip; setprio cluster) ----
    __builtin_amdgcn_s_setprio(1);
#pragma unroll
    for (int ks = 0; ks < 2; ++ks) {
      const int frp = wv * 16 + l15;
      const int cp = (ks * 4 + quad) ^ (l15 & 7);
      const short8 pf = *(const short8*)(smem + 57344 + (frp * 8 + cp) * 16);
#pragma unroll
      for (int dt = 0; dt < 4; ++dt) {
        const int vr = dt * 16 + l15;
        const short8 vf = *(const short8*)(vbase + (vr * 8 + cp) * 16);
        O[dt] = __builtin_amdgcn_mfma_f32_16x16x32_bf16(pf, vf, O[dt], 0, 0, 0);
      }
    }
    __builtin_amdgcn_s_setprio(0);
    cur ^= 1;
  }

  // denominator: reduce across the 16 lanes of each quad-row group
#pragma unroll
  for (int m = 1; m < 16; m <<= 1)
#pragma unroll
    for (int r = 0; r < 4; ++r)
      rden[r] += __shfl_xor(rden[r], m, 64);

  // write unnormalized fp32 partials + denominators
  float* const Op = sp ? Opart1 : Opart0;
  float* const dp = sp ? den1 : den0;
  const size_t ob = (size_t)(bn * 16 + it) * 64;
#pragma unroll
  for (int r = 0; r < 4; ++r) {
    const int il = wv * 16 + quad * 4 + r;
#pragma unroll
    for (int dt = 0; dt < 4; ++dt)
      Op[(ob + il) * 64 + dt * 16 + l15] = O[dt][r];
    if (l15 == 0) dp[ob + il] = rden[r];
  }
}

// ---------------------------------------------------------------------------
// combine j-split partials: AVb = bf16((O0+O1) / (d0+d1)). grid 1024.
// ---------------------------------------------------------------------------
__global__ __launch_bounds__(256) void attn_combine(
    const float* __restrict__ O0, const float* __restrict__ O1,
    const float* __restrict__ d0, const float* __restrict__ d1,
    unsigned short* __restrict__ AVb)
{
  const int blk = (int)blockIdx.x;           // bn*16 + it
  const int bn = blk >> 4, it = blk & 15;
  const int b = bn >> 4, n = bn & 15;
  const int tid = threadIdx.x;
  const int il = tid >> 2, ds = (tid & 3) * 16;
  const size_t base = ((size_t)blk * 64 + il) * 64 + ds;
  const float inv = 1.f / (d0[blk * 64 + il] + d1[blk * 64 + il]);
  short8 o0, o1;
#pragma unroll
  for (int g = 0; g < 2; ++g) {
    const float4 a = *(const float4*)(O0 + base + g * 8);
    const float4 bb = *(const float4*)(O1 + base + g * 8);
    const float4 a2 = *(const float4*)(O0 + base + g * 8 + 4);
    const float4 b2 = *(const float4*)(O1 + base + g * 8 + 4);
    short8& o = g ? o1 : o0;
    o[0] = (short)f2bf((a.x + bb.x) * inv);  o[1] = (short)f2bf((a.y + bb.y) * inv);
    o[2] = (short)f2bf((a.z + bb.z) * inv);  o[3] = (short)f2bf((a.w + bb.w) * inv);
    o[4] = (short)f2bf((a2.x + b2.x) * inv); o[5] = (short)f2bf((a2.y + b2.y) * inv);
    o[6] = (short)f2bf((a2.z + b2.z) * inv); o[7] = (short)f2bf((a2.w + b2.w) * inv);
  }
  unsigned short* op =
      AVb + ((size_t)(it * 64 + il) * BSZ + b) * DMODEL + n * DHEAD + ds;
  *(short8*)op = o0;
  *(short8*)(op + 8) = o1;
}

// ---------------------------------------------------------------------------
__global__ __launch_bounds__(256) void ln_kernel(
    float* __restrict__ X, const float* __restrict__ gw,
    const float* __restrict__ bw, unsigned short* __restrict__ bfo)
{
  const int row = blockIdx.x, tid = threadIdx.x;
  float* rp = X + (size_t)row * DMODEL;
  const float4 x = *(const float4*)(rp + tid * 4);
  float s = x.x + x.y + x.z + x.w;
  float q = x.x * x.x + x.y * x.y + x.z * x.z + x.w * x.w;
#pragma unroll
  for (int m = 1; m < 64; m <<= 1) {
    s += __shfl_xor(s, m, 64);
    q += __shfl_xor(q, m, 64);
  }
  __shared__ float ss[4], sq[4];
  if ((tid & 63) == 0) { ss[tid >> 6] = s; sq[tid >> 6] = q; }
  __syncthreads();
  s = ss[0] + ss[1] + ss[2] + ss[3];
  q = sq[0] + sq[1] + sq[2] + sq[3];
  const float mu = s * (1.f / DMODEL);
  const float var = q * (1.f / DMODEL) - mu * mu;
  const float rstd = rsqrtf(var + 1e-5f);
  const float4 g4 = *(const float4*)(gw + tid * 4);
  const float4 b4 = *(const float4*)(bw + tid * 4);
  float4 y;
  y.x = (x.x - mu) * rstd * g4.x + b4.x;
  y.y = (x.y - mu) * rstd * g4.y + b4.y;
  y.z = (x.z - mu) * rstd * g4.z + b4.z;
  y.w = (x.w - mu) * rstd * g4.w + b4.w;
  *(float4*)(rp + tid * 4) = y;
  if (bfo) {
    short4_t o;
    o[0] = (short)f2bf(y.x); o[1] = (short)f2bf(y.y);
    o[2] = (short)f2bf(y.z); o[3] = (short)f2bf(y.w);
    *(short4_t*)(bfo + (size_t)row * DMODEL + tid * 4) = o;
  }
}

// ---------------------------------------------------------------------------
extern "C" void kernel_launch(void* const* d_in, const int* in_sizes, int n_in,
                              void* d_out, int out_size, void* d_ws,
                              size_t ws_size, hipStream_t stream)
{
  const float* w       = (const float*)d_in[0];
  const float* r       = (const float*)d_in[1];
  const float* mems    = (const float*)d_in[2];
  const float* qkv_w   = (const float*)d_in[3];
  const float* r_net_w = (const float*)d_in[4];
  const float* o_w     = (const float*)d_in[5];
  const float* r_w_bias= (const float*)d_in[6];
  const float* r_r_bias= (const float*)d_in[7];
  const float* ln1_g   = (const float*)d_in[8];
  const float* ln1_b   = (const float*)d_in[9];
  const float* ff_w1   = (const float*)d_in[10];
  const float* ff_b1   = (const float*)d_in[11];
  const float* ff_w2   = (const float*)d_in[12];
  const float* ff_b2   = (const float*)d_in[13];
  const float* ln2_g   = (const float*)d_in[14];
  const float* ln2_b   = (const float*)d_in[15];
  float* out = (float*)d_out;

  // ---- workspace carve-up ----
  float* X1 = (float*)d_ws;                               // 4,194,304 f32
  unsigned short* Qh   = (unsigned short*)(X1 + 4194304); // 4,194,304 bf16
  unsigned short* Kh   = Qh + 4194304;                    // 8,388,608
  unsigned short* Vt   = Kh + 8388608;                    // 8,388,608
  unsigned short* Rk   = Vt + 8388608;                    // 2,097,152 (+8192 pad)
  unsigned short* Xcat = Rk + 2097152 + 8192;             // 8,388,608
  unsigned short* Wqkv = Xcat + 8388608;                  // 3,145,728
  unsigned short* Wr   = Wqkv + 3145728;                  // 1,048,576
  unsigned short* Wo   = Wr + 1048576;                    // 1,048,576
  unsigned short* W1   = Wo + 1048576;                    // 4,194,304
  unsigned short* W2   = W1 + 4194304;                    // 4,194,304
  float* den0 = (float*)(W2 + 4194304);                   // 65,536 f32
  float* den1 = den0 + 65536;                             // 65,536 f32
  unsigned short* AVb  = (unsigned short*)(den1 + 65536); // 4,194,304 bf16
  // aliases (disjoint lifetimes):
  unsigned short* Vh     = (unsigned short*)X1;  // qkv V (dead after transpose_v)
  unsigned short* Rb16   = AVb;                  // r bf16 (dead after rproj)
  float* Opart0          = (float*)X1;           // attn partial, split 0 (16MB)
  float* Opart1          = (float*)Xcat;         // attn partial, split 1 (16MB)
  unsigned short* X1b    = Qh;                   // ln1 bf16 (Qh dead after attn)
  unsigned short* H      = Kh;                   // ffn hidden (spans Kh+Vt)

  const dim3 blk(256);
  const dim3 blk2(512);

  // prep: 2 launches
  cast_all<<<dim3(5120), blk, 0, stream>>>(mems, w, r, Xcat, Rb16);
  transpose_all<<<dim3(3328), blk, 0, stream>>>(
      qkv_w, r_net_w, o_w, ff_w1, ff_w2, Wqkv, Wr, Wo, W1, W2);

  // 1a. KV-GEMM: cat x W[k|v] -> Kh, Vh (grid 256 = one exact round)
  mgemm2<0><<<dim3(8, 32), blk2, 0, stream>>>(
      Xcat, Wqkv + (size_t)1024 * 1024, nullptr, nullptr, Kh, Vh,
      DMODEL, 2048);
  // 1b. Q-GEMM: w-rows of cat only (rows 4096..8191) x W[q] -> Qh
  mgemm2<1><<<dim3(4, 16), blk2, 0, stream>>>(
      Xcat + (size_t)4096 * 1024, Wqkv, Qh, nullptr, nullptr, nullptr,
      DMODEL, 1024);
  transpose_v<<<dim3(32, 64), blk, 0, stream>>>(Vh, Vt);
  // 2. R projection -> Rk bf16
  mgemm<1, 64><<<dim3(16, 16), blk, 0, stream>>>(
      Rb16, Wr, nullptr, Rk, nullptr, nullptr, DMODEL, DMODEL);
  // 3. MFMA flash attention (j-split) -> fp32 partials; combine -> AVb bf16
  attn_mfma<<<dim3(32, 64), blk, 0, stream>>>(
      Qh, Kh, Vt, Rk, r_w_bias, r_r_bias, Opart0, Opart1, den0, den1);
  attn_combine<<<dim3(1024), blk, 0, stream>>>(Opart0, Opart1, den0, den1, AVb);
  // 4. o-proj + residual -> X1 fp32; LN1 (+X1b bf16)
  mgemm<2, 64><<<dim3(16, 32), blk, 0, stream>>>(
      AVb, Wo, X1, nullptr, nullptr, w, DMODEL, DMODEL);
  ln_kernel<<<dim3(4096), blk, 0, stream>>>(X1, ln1_g, ln1_b, X1b);
  // 5. FFN up + relu -> H bf16 (256^2 kernel)
  mgemm2<3><<<dim3(16, 16), blk2, 0, stream>>>(
      X1b, W1, H, ff_b1, nullptr, nullptr, DMODEL, DINNER);
  // 6. FFN down + bias + residual -> out fp32; LN2
  mgemm<4, 64><<<dim3(16, 32), blk, 0, stream>>>(
      H, W2, out, nullptr, ff_b2, X1, DINNER, DMODEL);
  ln_kernel<<<dim3(4096), blk, 0, stream>>>(out, ln2_g, ln2_b, nullptr);

  (void)in_sizes; (void)n_in; (void)out_size; (void)ws_size;
}

// Round 10
// 520.919 us; speedup vs baseline: 1.0137x; 1.0137x over previous
//
#include <hip/hip_runtime.h>
#include <math.h>

// ---------------------------------------------------------------------------
// MemTransformerLM (Transformer-XL layer) — round 16.
// attn: r14 form (no setprio — measured null, lockstep regime).
// QKV: fused again (r15 split's 64-block Q-GEMM was latency-bound, net null).
// mgemm (small GEMMs): TN=128 restored (r8-verified path) and applied to
//   rproj/o-proj/FFN-down — 128x128 tile doubles MFMA-per-barrier and halves
//   B traffic vs 128x64 (m92/m103: 64-col class 343 TF vs 128^2 912 TF).
//   Grids become exact 1-block/CU rounds: 128 / 256 / 256 blocks.
// ---------------------------------------------------------------------------

#define QLEN 1024
#define BSZ  4
#define DMODEL 1024
#define NHEAD 16
#define DHEAD 64
#define DINNER 4096
#define MEMLEN 1024
#define KLEN 2048

typedef __attribute__((ext_vector_type(8))) short short8;
typedef __attribute__((ext_vector_type(4))) short short4_t;
typedef __attribute__((ext_vector_type(4))) float f32x4;

__device__ __forceinline__ unsigned short f2bf(float x) {
  union { float f; unsigned u; } cv; cv.f = x;
  const unsigned u = cv.u;
  return (unsigned short)((u + 0x7FFFu + ((u >> 16) & 1u)) >> 16);
}
__device__ __forceinline__ float bf2f(unsigned short b) {
  union { unsigned u; float f; } cv; cv.u = ((unsigned)b) << 16;
  return cv.f;
}

__device__ __forceinline__ void gload16(const void* g, void* l) {
  __builtin_amdgcn_global_load_lds(
      (const __attribute__((address_space(1))) unsigned int*)g,
      (__attribute__((address_space(3))) unsigned int*)l, 16, 0, 0);
}

__device__ __forceinline__ int chidx(int row, int kc) {
  return row * 4 + (kc ^ ((row >> 1) & 3));
}

// ---------------------------------------------------------------------------
// mgemm2: C[M,N] = A[M,K] @ Bt[N,K]^T, 256x256 tile, BK=32, 512 threads.
// Depth-2 pipeline, 96KB LDS (3 bufs), vmcnt(8/4/0) ladder. 2 barriers/tile.
// MODE 0: QKV fused (sec 0=Q guarded, 1=K, 2=V). MODE 3: FFN up+bias+relu.
// Epilogue: LDS-staged vectorized C-store (wave-private 8KB regions).
// ---------------------------------------------------------------------------
template<int MODE>
__global__ __launch_bounds__(512) void mgemm2(
    const unsigned short* __restrict__ A, const unsigned short* __restrict__ Bt,
    unsigned short* __restrict__ Cb, const float* __restrict__ aux,
    unsigned short* __restrict__ oK, unsigned short* __restrict__ oV,
    int Kdim, int N)
{
  __shared__ __align__(16) char smem[98304];

  const int tid = threadIdx.x;
  const int lane = tid & 63, wv = tid >> 6;
  const int wr = wv >> 2, wc = wv & 3;
  const int quad = lane >> 4, l15 = lane & 15;

  const int gx = (int)gridDim.x;
  const int nwg = gx * (int)gridDim.y;
  const int flat = (int)blockIdx.y * gx + (int)blockIdx.x;
  const int swz = (flat & 7) * (nwg >> 3) + (flat >> 3);
  const int m0 = (swz / gx) * 256, n0 = (swz % gx) * 256;

  const int srow = tid >> 2;
  const int skc = (tid & 3) ^ ((srow >> 1) & 3);
  const unsigned short* pA0 = A + (size_t)(m0 + srow) * Kdim + skc * 8;
  const unsigned short* pA1 = A + (size_t)(m0 + 128 + srow) * Kdim + skc * 8;
  const unsigned short* pB0 = Bt + (size_t)(n0 + srow) * Kdim + skc * 8;
  const unsigned short* pB1 = Bt + (size_t)(n0 + 128 + srow) * Kdim + skc * 8;
  const int wb = (tid & 448) * 16;          // wave-uniform LDS base

  const int cch = (quad ^ ((l15 >> 1) & 3)) * 16;
  const int aoffb = wr * 8192 + l15 * 64 + cch;                      // +i*1024
  const int boffb = (wc >> 1) * 8192 + ((wc & 1) * 64 + l15) * 64 + cch;

  f32x4 acc[8][4] = {};

  const int nkt = Kdim >> 5;
  // prologue: stage kt=0 -> buf0, kt=1 -> buf1 (8 loads outstanding)
  gload16(pA0, smem + wb);
  gload16(pA1, smem + 8192 + wb);
  gload16(pB0, smem + 49152 + wb);
  gload16(pB1, smem + 57344 + wb);
  pA0 += 32; pA1 += 32; pB0 += 32; pB1 += 32;
  gload16(pA0, smem + 16384 + wb);
  gload16(pA1, smem + 24576 + wb);
  gload16(pB0, smem + 65536 + wb);
  gload16(pB1, smem + 73728 + wb);
  pA0 += 32; pA1 += 32; pB0 += 32; pB1 += 32;

  int rbuf = 0;
  for (int kt = 0; kt < nkt; ++kt) {
    if (kt + 2 < nkt) {
      int wb3 = rbuf + 2; if (wb3 >= 3) wb3 -= 3;
      const int ab = wb3 * 16384, bb = 49152 + wb3 * 16384;
      gload16(pA0, smem + ab + wb);
      gload16(pA1, smem + ab + 8192 + wb);
      gload16(pB0, smem + bb + wb);
      gload16(pB1, smem + bb + 8192 + wb);
      pA0 += 32; pA1 += 32; pB0 += 32; pB1 += 32;
      asm volatile("s_waitcnt vmcnt(8)" ::: "memory");
    } else if (kt + 1 < nkt) {
      asm volatile("s_waitcnt vmcnt(4)" ::: "memory");
    } else {
      asm volatile("s_waitcnt vmcnt(0)" ::: "memory");
    }
    __builtin_amdgcn_s_barrier();            // A: buf rbuf staged & visible

    const char* const abuf = smem + rbuf * 16384;
    const char* const bbuf = smem + 49152 + rbuf * 16384;

    // ---- phase 0: B all + A rows 0..63 ----
    short8 bfr[4], af[4];
#pragma unroll
    for (int j = 0; j < 4; ++j)
      bfr[j] = *(const short8*)(bbuf + boffb + j * 1024);
#pragma unroll
    for (int i = 0; i < 4; ++i)
      af[i] = *(const short8*)(abuf + aoffb + i * 1024);
    __builtin_amdgcn_s_setprio(1);
#pragma unroll
    for (int i = 0; i < 4; ++i)
#pragma unroll
      for (int j = 0; j < 4; ++j)
        acc[i][j] = __builtin_amdgcn_mfma_f32_16x16x32_bf16(
            af[i], bfr[j], acc[i][j], 0, 0, 0);
    __builtin_amdgcn_s_setprio(0);

    // ---- phase 1: A rows 64..127 (same staged buffer; no barrier needed) ----
#pragma unroll
    for (int i = 0; i < 4; ++i)
      af[i] = *(const short8*)(abuf + aoffb + (i + 4) * 1024);
    __builtin_amdgcn_s_setprio(1);
#pragma unroll
    for (int i = 0; i < 4; ++i)
#pragma unroll
      for (int j = 0; j < 4; ++j)
        acc[i + 4][j] = __builtin_amdgcn_mfma_f32_16x16x32_bf16(
            af[i], bfr[j], acc[i + 4][j], 0, 0, 0);
    __builtin_amdgcn_s_setprio(0);
    asm volatile("s_waitcnt lgkmcnt(0)" ::: "memory");
    __builtin_amdgcn_s_barrier();            // E: all reads of buf rbuf done
    rbuf += 1; if (rbuf == 3) rbuf = 0;
  }

  // ---- epilogue: LDS-staged vectorized C-store ----
  const int cbw = n0 + wc * 64;              // wave-uniform col base
  float bias[4];
  if constexpr (MODE == 3) {
#pragma unroll
    for (int j = 0; j < 4; ++j) bias[j] = aux[cbw + j * 16 + l15];
  }
  unsigned short* const eb = (unsigned short*)(smem + wv * 8192);
  for (int half = 0; half < 2; ++half) {
#pragma unroll
    for (int ii = 0; ii < 4; ++ii) {
#pragma unroll
      for (int r = 0; r < 4; ++r) {
        const int lr = ii * 16 + quad * 4 + r;
#pragma unroll
        for (int j = 0; j < 4; ++j) {
          float v = acc[half * 4 + ii][j][r];
          if constexpr (MODE == 3) v = fmaxf(v + bias[j], 0.f);
          const int slot = (j * 2 + (l15 >> 3)) ^ (lr & 7);
          eb[lr * 64 + slot * 8 + (l15 & 7)] = f2bf(v);
        }
      }
    }
    const int grow = m0 + wr * 128 + half * 64 + lane;
    short8 row[8];
#pragma unroll
    for (int g = 0; g < 8; ++g)
      row[g] = *(const short8*)(eb + lane * 64 + ((g ^ (lane & 7)) * 8));
    if constexpr (MODE == 0) {               // QKV: sec 0=Q(guarded) 1=K 2=V
      const int kkg = grow >> 2, b2 = grow & 3;
      const int sec = cbw >> 10, hn = (cbw >> 6) & 15;
      unsigned short* dst = nullptr;
      bool doit = true;
      if (sec == 0) {
        doit = (kkg >= MEMLEN);
        dst = Cb + ((size_t)(b2 * NHEAD + hn) * QLEN + (kkg - MEMLEN)) * DHEAD;
      } else if (sec == 1) {
        dst = oK + ((size_t)(b2 * NHEAD + hn) * KLEN + kkg) * DHEAD;
      } else {
        dst = oV + ((size_t)(b2 * NHEAD + hn) * KLEN + kkg) * DHEAD;
      }
      if (doit) {
#pragma unroll
        for (int g = 0; g < 8; ++g) *(short8*)(dst + g * 8) = row[g];
      }
    } else {
      unsigned short* dst = Cb + (size_t)grow * N + cbw;
#pragma unroll
      for (int g = 0; g < 8; ++g) *(short8*)(dst + g * 8) = row[g];
    }
  }
}

// ---------------------------------------------------------------------------
// bf16 MFMA GEMM: 128xTN tile, BK=32, 4 waves, depth-2 (3 bufs).
// TN=128 restored (r8-verified): 4 loads/step, vmcnt(8/4/0); TN=64: 3 loads,
// vmcnt(6/3/0). Used for rproj (MODE 1), o-proj (2), FFN-down (4) at TN=128.
// ---------------------------------------------------------------------------
template<int MODE, int TN>
__global__ __launch_bounds__(256) void mgemm(
    const unsigned short* __restrict__ A, const unsigned short* __restrict__ Bt,
    float* __restrict__ C, unsigned short* __restrict__ Cb,
    const float* __restrict__ aux, const float* __restrict__ res,
    int Kdim, int N)
{
  constexpr int BUF = 8192 + TN * 64;          // bytes per stage buffer
  __shared__ __align__(16) char smem[3 * BUF];

  const int tid = threadIdx.x;
  const int lane = tid & 63, wv = tid >> 6;

  const int gx = (int)gridDim.x;
  const int nwg = gx * (int)gridDim.y;
  const int flat = (int)blockIdx.y * gx + (int)blockIdx.x;
  const int swz = (flat & 7) * (nwg >> 3) + (flat >> 3);
  const int m0 = (swz / gx) * 128, n0 = (swz % gx) * TN;

  const unsigned short *gA0, *gA1, *gB0, *gB1 = nullptr;
  {
    int c = tid, m = c >> 2, kc = (c & 3) ^ ((m >> 1) & 3);
    gA0 = A + (size_t)(m0 + m) * Kdim + kc * 8;
    c = 256 + tid; m = c >> 2; kc = (c & 3) ^ ((m >> 1) & 3);
    gA1 = A + (size_t)(m0 + m) * Kdim + kc * 8;
    c = tid; int nn = c >> 2; kc = (c & 3) ^ ((nn >> 1) & 3);
    gB0 = Bt + (size_t)(n0 + nn) * Kdim + kc * 8;
    if constexpr (TN == 128) {
      c = 256 + tid; nn = c >> 2; kc = (c & 3) ^ ((nn >> 1) & 3);
      gB1 = Bt + (size_t)(n0 + nn) * Kdim + kc * 8;
    }
  }
  const int wvoff = (tid & 192) * 16;

  const int fr = lane & 15, kq = lane >> 4;
  constexpr int NJ = TN / 32;
  int aoff[4], boff[NJ];
#pragma unroll
  for (int t = 0; t < 4; ++t) {
    const int ra = (wv & 1) * 64 + t * 16 + fr;
    aoff[t] = chidx(ra, kq) * 16;
  }
#pragma unroll
  for (int t = 0; t < NJ; ++t) {
    const int rb = (wv >> 1) * (TN / 2) + t * 16 + fr;
    boff[t] = 8192 + chidx(rb, kq) * 16;
  }

  f32x4 acc[4][NJ] = {};

  // prologue: stage step 0 -> buf0, step 1 -> buf1
  {
    char* const b0 = smem + wvoff;
    gload16(gA0, b0);
    gload16(gA1, b0 + 4096);
    gload16(gB0, b0 + 8192);
    if constexpr (TN == 128) gload16(gB1, b0 + 12288);
    gA0 += 32; gA1 += 32; gB0 += 32;
    if constexpr (TN == 128) gB1 += 32;
    char* const b1 = smem + BUF + wvoff;
    gload16(gA0, b1);
    gload16(gA1, b1 + 4096);
    gload16(gB0, b1 + 8192);
    if constexpr (TN == 128) gload16(gB1, b1 + 12288);
    gA0 += 32; gA1 += 32; gB0 += 32;
    if constexpr (TN == 128) gB1 += 32;
  }

  int rbuf = 0;
  for (int k0 = 0; k0 < Kdim; k0 += 32) {
    if (k0 + 64 < Kdim) {
      int wb3 = rbuf + 2; if (wb3 >= 3) wb3 -= 3;
      char* const nb = smem + wb3 * BUF + wvoff;
      gload16(gA0, nb);
      gload16(gA1, nb + 4096);
      gload16(gB0, nb + 8192);
      if constexpr (TN == 128) gload16(gB1, nb + 12288);
      gA0 += 32; gA1 += 32; gB0 += 32;
      if constexpr (TN == 128) gB1 += 32;
      if constexpr (TN == 128)
        asm volatile("s_waitcnt vmcnt(8)" ::: "memory");
      else
        asm volatile("s_waitcnt vmcnt(6)" ::: "memory");
    } else if (k0 + 32 < Kdim) {
      if constexpr (TN == 128)
        asm volatile("s_waitcnt vmcnt(4)" ::: "memory");
      else
        asm volatile("s_waitcnt vmcnt(3)" ::: "memory");
    } else {
      asm volatile("s_waitcnt vmcnt(0)" ::: "memory");
    }
    __builtin_amdgcn_s_barrier();          // buffer `rbuf` fully staged

    const char* const cb = smem + rbuf * BUF;
    short8 af[4], bfr[NJ];
#pragma unroll
    for (int t = 0; t < 4; ++t) af[t] = *(const short8*)(cb + aoff[t]);
#pragma unroll
    for (int t = 0; t < NJ; ++t) bfr[t] = *(const short8*)(cb + boff[t]);
#pragma unroll
    for (int i = 0; i < 4; ++i)
#pragma unroll
      for (int j = 0; j < NJ; ++j)
        acc[i][j] = __builtin_amdgcn_mfma_f32_16x16x32_bf16(
            af[i], bfr[j], acc[i][j], 0, 0, 0);

    asm volatile("s_waitcnt lgkmcnt(0)" ::: "memory");
    __builtin_amdgcn_s_barrier();          // all reads of `rbuf` done
    rbuf += 1; if (rbuf == 3) rbuf = 0;
  }

  const int rbase = m0 + (wv & 1) * 64 + (lane >> 4) * 4;
  const int cbase = n0 + (wv >> 1) * (TN / 2) + (lane & 15);
#pragma unroll
  for (int i = 0; i < 4; ++i) {
#pragma unroll
    for (int r = 0; r < 4; ++r) {
      const int grow = rbase + i * 16 + r;
#pragma unroll
      for (int j = 0; j < NJ; ++j) {
        const int gcol = cbase + j * 16;
        const float v = acc[i][j][r];
        if constexpr (MODE == 1) {
          const int hn = gcol >> 6, d = gcol & 63;
          Cb[((size_t)hn * KLEN + grow) * DHEAD + d] = f2bf(v);
        } else if constexpr (MODE == 2) {
          C[(size_t)grow * N + gcol] = v + res[(size_t)grow * N + gcol];
        } else {
          C[(size_t)grow * N + gcol] = v + aux[gcol] + res[(size_t)grow * N + gcol];
        }
      }
    }
  }
}

// ---------------------------------------------------------------------------
// Vh [bn][j][d] bf16 -> Vt [bn][d][j] bf16.
// ---------------------------------------------------------------------------
__global__ __launch_bounds__(256) void transpose_v(
    const unsigned short* __restrict__ Vh, unsigned short* __restrict__ Vt)
{
  __shared__ unsigned short t[64 * 80];
  const int j0 = (int)blockIdx.x * 64;
  const int bn = (int)blockIdx.y;
  const int tid = threadIdx.x;
#pragma unroll
  for (int it = 0; it < 2; ++it) {
    const int f = it * 256 + tid;
    const int j = f >> 3, d8 = (f & 7) * 8;
    const short8 v = *(const short8*)(Vh + ((size_t)bn * KLEN + j0 + j) * DHEAD + d8);
    *(short8*)(t + j * 80 + d8) = v;
  }
  __syncthreads();
  const int d = tid >> 2, jseg = (tid & 3) * 16;
  short8 o0, o1;
#pragma unroll
  for (int e = 0; e < 8; ++e) o0[e] = (short)t[(jseg + e) * 80 + d];
#pragma unroll
  for (int e = 0; e < 8; ++e) o1[e] = (short)t[(jseg + 8 + e) * 80 + d];
  unsigned short* op = Vt + ((size_t)bn * DHEAD + d) * KLEN + j0 + jseg;
  *(short8*)op = o0;
  *(short8*)(op + 8) = o1;
}

// ---------------------------------------------------------------------------
// merged input casts: mems|w -> Xcat, r -> Rb16. grid 5120.
// ---------------------------------------------------------------------------
__global__ __launch_bounds__(256) void cast_all(
    const float* __restrict__ mems, const float* __restrict__ w,
    const float* __restrict__ r, unsigned short* __restrict__ Xcat,
    unsigned short* __restrict__ Rb16)
{
  const size_t i = ((size_t)blockIdx.x * 256 + threadIdx.x) * 8;
  const float* src;
  unsigned short* dst;
  if (i < 4194304)       { src = mems + i;          dst = Xcat + i; }
  else if (i < 8388608)  { src = w + (i - 4194304); dst = Xcat + i; }
  else                   { src = r + (i - 8388608); dst = Rb16 + (i - 8388608); }
  const float4 x = *(const float4*)src;
  const float4 y = *(const float4*)(src + 4);
  short8 v;
  v[0] = (short)f2bf(x.x); v[1] = (short)f2bf(x.y);
  v[2] = (short)f2bf(x.z); v[3] = (short)f2bf(x.w);
  v[4] = (short)f2bf(y.x); v[5] = (short)f2bf(y.y);
  v[6] = (short)f2bf(y.z); v[7] = (short)f2bf(y.w);
  *(short8*)dst = v;
}

// ---------------------------------------------------------------------------
// merged weight transposes: fp32 [R][C] -> bf16 [C][R], 5 weights. grid 3328.
// ---------------------------------------------------------------------------
__global__ __launch_bounds__(256) void transpose_all(
    const float* __restrict__ qkv_w, const float* __restrict__ r_net_w,
    const float* __restrict__ o_w, const float* __restrict__ ff_w1,
    const float* __restrict__ ff_w2,
    unsigned short* __restrict__ Wqkv, unsigned short* __restrict__ Wr,
    unsigned short* __restrict__ Wo, unsigned short* __restrict__ W1,
    unsigned short* __restrict__ W2)
{
  const int bid = (int)blockIdx.x;
  const float* in; unsigned short* out; int R, C, xt, loc;
  if (bid < 768)        { in = qkv_w;   out = Wqkv; R = 1024; C = 3072; xt = 48; loc = bid; }
  else if (bid < 1024)  { in = r_net_w; out = Wr;   R = 1024; C = 1024; xt = 16; loc = bid - 768; }
  else if (bid < 1280)  { in = o_w;     out = Wo;   R = 1024; C = 1024; xt = 16; loc = bid - 1024; }
  else if (bid < 2304)  { in = ff_w1;   out = W1;   R = 1024; C = 4096; xt = 64; loc = bid - 1280; }
  else                  { in = ff_w2;   out = W2;   R = 4096; C = 1024; xt = 16; loc = bid - 2304; }
  const int c0 = (loc % xt) * 64, r0 = (loc / xt) * 64;

  __shared__ float t[64][65];
  const int tid = threadIdx.x;
  const int rr = tid >> 4, cc = (tid & 15) * 4;
#pragma unroll
  for (int it = 0; it < 4; ++it) {
    const int rw = rr + it * 16;
    const float4 v = *(const float4*)(in + (size_t)(r0 + rw) * C + c0 + cc);
    t[rw][cc] = v.x; t[rw][cc + 1] = v.y; t[rw][cc + 2] = v.z; t[rw][cc + 3] = v.w;
  }
  __syncthreads();
  const int oc = tid >> 2, ob = (tid & 3) * 16;
#pragma unroll
  for (int j4 = 0; j4 < 4; ++j4) {
    short4_t o;
#pragma unroll
    for (int j = 0; j < 4; ++j) o[j] = (short)f2bf(t[ob + j4 * 4 + j][oc]);
    *(short4_t*)(out + (size_t)(c0 + oc) * R + r0 + ob + j4 * 4) = o;
  }
}

// ---------------------------------------------------------------------------
// MFMA flash relative attention (r14 form — best measured, 144.4us).
// Block = 4 waves; i-tile 64; j-split 2. grid 2048 flattened + XCD swizzle.
// LDS 64KB: K dbuf 2x8K @0 | V dbuf 2x8K @16K | R-ring 192 rows (24K) @32K |
//           Ps 8K @57344 (wave-private).
// ---------------------------------------------------------------------------
__global__ __launch_bounds__(256, 2) void attn_mfma(
    const unsigned short* __restrict__ Qh, const unsigned short* __restrict__ Kh,
    const unsigned short* __restrict__ Vt, const unsigned short* __restrict__ Rk,
    const float* __restrict__ rwb, const float* __restrict__ rrb,
    float* __restrict__ Opart0, float* __restrict__ Opart1,
    float* __restrict__ den0, float* __restrict__ den1)
{
  __shared__ __align__(16) char smem[65536];

  const int tid = threadIdx.x;
  const int lane = tid & 63, wv = tid >> 6;
  const int quad = lane >> 4, l15 = lane & 15;

  const int bid0 = (int)blockIdx.y * 32 + (int)blockIdx.x;
  const int slot = bid0 >> 3;
  const int bn = (bid0 & 7) * 8 + (slot >> 5);
  const int inner = slot & 31;
  const int it = inner >> 1, sp = inner & 1;
  const int i0 = it * 64;
  const int n = bn & 15;

  const int nch = 17 + it;
  const int h = (nch + 1) >> 1;
  const int lo = sp ? h : 0, hi = sp ? nch : h;

  const unsigned short* __restrict__ Qb = Qh + (size_t)bn * QLEN * DHEAD;
  const unsigned short* __restrict__ Kb = Kh + (size_t)bn * KLEN * DHEAD;
  const unsigned short* __restrict__ Vb = Vt + (size_t)bn * DHEAD * KLEN;
  const unsigned short* __restrict__ Rb = Rk + (size_t)n * KLEN * DHEAD;

  // persistent Q fragments with biases folded
  short8 qk[2], qr[2];
  {
    const int qrow = i0 + wv * 16 + l15;
    const unsigned short* qp = Qb + (size_t)qrow * DHEAD + quad * 8;
    const float* wp = rwb + n * DHEAD + quad * 8;
    const float* rp = rrb + n * DHEAD + quad * 8;
#pragma unroll
    for (int ks = 0; ks < 2; ++ks) {
      const short8 q8 = *(const short8*)(qp + ks * 32);
#pragma unroll
      for (int e = 0; e < 8; ++e) {
        const float qv = bf2f((unsigned short)q8[e]);
        qk[ks][e] = (short)f2bf(qv + wp[ks * 32 + e]);
        qr[ks][e] = (short)f2bf(qv + rp[ks * 32 + e]);
      }
    }
  }

  // bpermute lane maps + selectors (per register r)
  int srcl[4];
  bool condE[4];
#pragma unroll
  for (int r = 0; r < 4; ++r) {
    const int E = l15 - quad * 4 - r + 15;           // in [0,30]
    srcl[r] = (lane & 48) | (E & 15);
    condE[r] = (E >= 16);
  }

  f32x4 O[4] = {};
  float rden[4] = {0.f, 0.f, 0.f, 0.f};
  const int wvoff = (tid & 192) * 16;

  // ---- prologue: stage chunk `lo` into buffer 0 + full 128-row R window ----
  {
    const int j0 = lo * 64;
    const int g64 = lo - it + 15;                    // window start / 64
    const int rb3 = (g64 % 3) * 64;                  // ring phys base row
#pragma unroll
    for (int t2 = 0; t2 < 2; ++t2) {
      const int s = t2 * 256 + tid;
      const int row = s >> 3, kc = (s & 7) ^ (row & 7);
      gload16(Kb + (((size_t)(j0 + row)) << 6) + kc * 8,
              smem + t2 * 4096 + wvoff);
    }
#pragma unroll
    for (int t2 = 0; t2 < 2; ++t2) {
      const int s = t2 * 256 + tid;
      const int row = s >> 3, kc = (s & 7) ^ (row & 7);
      gload16(Vb + (((size_t)row) << 11) + j0 + kc * 8,
              smem + 16384 + t2 * 4096 + wvoff);
    }
    const int gw = j0 - i0 + 960;
#pragma unroll
    for (int t2 = 0; t2 < 4; ++t2) {
      const int rr = t2 * 32 + (tid >> 3);
      const int gr = gw + rr;
      const int kc = (tid & 7) ^ (rr & 7);
      int pb = rb3 + t2 * 32; if (pb >= 192) pb -= 192;
      gload16(Rb + (((size_t)gr) << 6) + kc * 8,
              smem + 32768 + pb * 128 + wvoff);
    }
  }

  int cur = 0;
  for (int ch = lo; ch < hi; ++ch) {
    const int j0 = ch * 64;
    const int g64 = ch - it + 15;
    const int rb3 = (g64 % 3) * 64;
    const int gw = j0 - i0 + 960;

    asm volatile("s_waitcnt lgkmcnt(0)" ::: "memory");
    __builtin_amdgcn_s_barrier();                    // A: prior reads done

    if (ch + 1 < hi) {
      // prefetch chunk ch+1: K,V into buffer cur^1; R rel rows [128,192)
      const int nb = cur ^ 1;
      const int j0n = j0 + 64;
#pragma unroll
      for (int t2 = 0; t2 < 2; ++t2) {
        const int s = t2 * 256 + tid;
        const int row = s >> 3, kc = (s & 7) ^ (row & 7);
        gload16(Kb + (((size_t)(j0n + row)) << 6) + kc * 8,
                smem + nb * 8192 + t2 * 4096 + wvoff);
      }
#pragma unroll
      for (int t2 = 0; t2 < 2; ++t2) {
        const int s = t2 * 256 + tid;
        const int row = s >> 3, kc = (s & 7) ^ (row & 7);
        gload16(Vb + (((size_t)row) << 11) + j0n + kc * 8,
                smem + 16384 + nb * 8192 + t2 * 4096 + wvoff);
      }
#pragma unroll
      for (int t2 = 0; t2 < 2; ++t2) {
        const int rr = t2 * 32 + (tid >> 3);
        const int gr = gw + 128 + rr;                // pad in Rk covers <=2111
        const int kc = (tid & 7) ^ (rr & 7);
        int pb = rb3 + 128 + t2 * 32; if (pb >= 192) pb -= 192;
        gload16(Rb + (((size_t)gr) << 6) + kc * 8,
                smem + 32768 + pb * 128 + wvoff);
      }
      asm volatile("s_waitcnt vmcnt(6)" ::: "memory");   // ch's loads landed
    } else {
      asm volatile("s_waitcnt vmcnt(0)" ::: "memory");
    }
    __builtin_amdgcn_s_barrier();                    // B: chunk ch visible

    const char* const kbase = smem + cur * 8192;
    const char* const vbase = smem + 16384 + cur * 8192;

    // ---- S_K = (q+rwb)·k ----
    f32x4 sk[4];
#pragma unroll
    for (int jt = 0; jt < 4; ++jt) {
      f32x4 a = {0.f, 0.f, 0.f, 0.f};
#pragma unroll
      for (int ks = 0; ks < 2; ++ks) {
        const int frr = jt * 16 + l15;
        const int c = (ks * 4 + quad) ^ (l15 & 7);
        const short8 kf = *(const short8*)(kbase + (frr * 8 + c) * 16);
        a = __builtin_amdgcn_mfma_f32_16x16x32_bf16(qk[ks], kf, a, 0, 0, 0);
      }
      sk[jt] = a;
    }
    // ---- U = (q+rrb)·r band: 5 tiles (window-relative tiles 3-wv+s) ----
    f32x4 uu[5];
#pragma unroll
    for (int s = 0; s < 5; ++s) {
      f32x4 a = {0.f, 0.f, 0.f, 0.f};
      int frr = rb3 + (3 - wv + s) * 16 + l15;       // phys ring row
      if (frr >= 192) frr -= 192;
#pragma unroll
      for (int ks = 0; ks < 2; ++ks) {
        const int c = (ks * 4 + quad) ^ (l15 & 7);
        const short8 rf = *(const short8*)(smem + 32768 + (frr * 8 + c) * 16);
        a = __builtin_amdgcn_mfma_f32_16x16x32_bf16(qr[ks], rf, a, 0, 0, 0);
      }
      uu[s] = a;
    }

    // ---- band rotate via bpermute: rot[s][r] = uu[s][r] from lane srcl[r] ----
    float rot[5][4];
#pragma unroll
    for (int s = 0; s < 5; ++s)
#pragma unroll
      for (int r = 0; r < 4; ++r)
        rot[s][r] = __shfl(uu[s][r], srcl[r], 64);

    // ---- P = exp((S_K + U)/8), masked (branchless); Ps wave-private ----
    unsigned short* const Ps = (unsigned short*)(smem + 57344);
#pragma unroll
    for (int jt = 0; jt < 4; ++jt) {
      const int jl = jt * 16 + l15;
#pragma unroll
      for (int r = 0; r < 4; ++r) {
        const int il = wv * 16 + quad * 4 + r;
        const int dj = (j0 + jl) - (i0 + il);
        const float uv = condE[r] ? rot[jt + 1][r] : rot[jt][r];
        const float sv = (sk[jt][r] + uv) * 0.125f;
        const float p = (dj <= 1024) ? __expf(sv) : 0.f;
        rden[r] += p;
        Ps[(il * 8 + ((jl >> 3) ^ (il & 7))) * 8 + (jl & 7)] = f2bf(p);
      }
    }

    // ---- O += P @ V (wave-private P strip) ----
#pragma unroll
    for (int ks = 0; ks < 2; ++ks) {
      const int frp = wv * 16 + l15;
      const int cp = (ks * 4 + quad) ^ (l15 & 7);
      const short8 pf = *(const short8*)(smem + 57344 + (frp * 8 + cp) * 16);
#pragma unroll
      for (int dt = 0; dt < 4; ++dt) {
        const int vr = dt * 16 + l15;
        const short8 vf = *(const short8*)(vbase + (vr * 8 + cp) * 16);
        O[dt] = __builtin_amdgcn_mfma_f32_16x16x32_bf16(pf, vf, O[dt], 0, 0, 0);
      }
    }
    cur ^= 1;
  }

  // denominator: reduce across the 16 lanes of each quad-row group
#pragma unroll
  for (int m = 1; m < 16; m <<= 1)
#pragma unroll
    for (int r = 0; r < 4; ++r)
      rden[r] += __shfl_xor(rden[r], m, 64);

  // write unnormalized fp32 partials + denominators
  float* const Op = sp ? Opart1 : Opart0;
  float* const dp = sp ? den1 : den0;
  const size_t ob = (size_t)(bn * 16 + it) * 64;
#pragma unroll
  for (int r = 0; r < 4; ++r) {
    const int il = wv * 16 + quad * 4 + r;
#pragma unroll
    for (int dt = 0; dt < 4; ++dt)
      Op[(ob + il) * 64 + dt * 16 + l15] = O[dt][r];
    if (l15 == 0) dp[ob + il] = rden[r];
  }
}

// ---------------------------------------------------------------------------
// combine j-split partials: AVb = bf16((O0+O1) / (d0+d1)). grid 1024.
// ---------------------------------------------------------------------------
__global__ __launch_bounds__(256) void attn_combine(
    const float* __restrict__ O0, const float* __restrict__ O1,
    const float* __restrict__ d0, const float* __restrict__ d1,
    unsigned short* __restrict__ AVb)
{
  const int blk = (int)blockIdx.x;           // bn*16 + it
  const int bn = blk >> 4, it = blk & 15;
  const int b = bn >> 4, n = bn & 15;
  const int tid = threadIdx.x;
  const int il = tid >> 2, ds = (tid & 3) * 16;
  const size_t base = ((size_t)blk * 64 + il) * 64 + ds;
  const float inv = 1.f / (d0[blk * 64 + il] + d1[blk * 64 + il]);
  short8 o0, o1;
#pragma unroll
  for (int g = 0; g < 2; ++g) {
    const float4 a = *(const float4*)(O0 + base + g * 8);
    const float4 bb = *(const float4*)(O1 + base + g * 8);
    const float4 a2 = *(const float4*)(O0 + base + g * 8 + 4);
    const float4 b2 = *(const float4*)(O1 + base + g * 8 + 4);
    short8& o = g ? o1 : o0;
    o[0] = (short)f2bf((a.x + bb.x) * inv);  o[1] = (short)f2bf((a.y + bb.y) * inv);
    o[2] = (short)f2bf((a.z + bb.z) * inv);  o[3] = (short)f2bf((a.w + bb.w) * inv);
    o[4] = (short)f2bf((a2.x + b2.x) * inv); o[5] = (short)f2bf((a2.y + b2.y) * inv);
    o[6] = (short)f2bf((a2.z + b2.z) * inv); o[7] = (short)f2bf((a2.w + b2.w) * inv);
  }
  unsigned short* op =
      AVb + ((size_t)(it * 64 + il) * BSZ + b) * DMODEL + n * DHEAD + ds;
  *(short8*)op = o0;
  *(short8*)(op + 8) = o1;
}

// ---------------------------------------------------------------------------
__global__ __launch_bounds__(256) void ln_kernel(
    float* __restrict__ X, const float* __restrict__ gw,
    const float* __restrict__ bw, unsigned short* __restrict__ bfo)
{
  const int row = blockIdx.x, tid = threadIdx.x;
  float* rp = X + (size_t)row * DMODEL;
  const float4 x = *(const float4*)(rp + tid * 4);
  float s = x.x + x.y + x.z + x.w;
  float q = x.x * x.x + x.y * x.y + x.z * x.z + x.w * x.w;
#pragma unroll
  for (int m = 1; m < 64; m <<= 1) {
    s += __shfl_xor(s, m, 64);
    q += __shfl_xor(q, m, 64);
  }
  __shared__ float ss[4], sq[4];
  if ((tid & 63) == 0) { ss[tid >> 6] = s; sq[tid >> 6] = q; }
  __syncthreads();
  s = ss[0] + ss[1] + ss[2] + ss[3];
  q = sq[0] + sq[1] + sq[2] + sq[3];
  const float mu = s * (1.f / DMODEL);
  const float var = q * (1.f / DMODEL) - mu * mu;
  const float rstd = rsqrtf(var + 1e-5f);
  const float4 g4 = *(const float4*)(gw + tid * 4);
  const float4 b4 = *(const float4*)(bw + tid * 4);
  float4 y;
  y.x = (x.x - mu) * rstd * g4.x + b4.x;
  y.y = (x.y - mu) * rstd * g4.y + b4.y;
  y.z = (x.z - mu) * rstd * g4.z + b4.z;
  y.w = (x.w - mu) * rstd * g4.w + b4.w;
  *(float4*)(rp + tid * 4) = y;
  if (bfo) {
    short4_t o;
    o[0] = (short)f2bf(y.x); o[1] = (short)f2bf(y.y);
    o[2] = (short)f2bf(y.z); o[3] = (short)f2bf(y.w);
    *(short4_t*)(bfo + (size_t)row * DMODEL + tid * 4) = o;
  }
}

// ---------------------------------------------------------------------------
extern "C" void kernel_launch(void* const* d_in, const int* in_sizes, int n_in,
                              void* d_out, int out_size, void* d_ws,
                              size_t ws_size, hipStream_t stream)
{
  const float* w       = (const float*)d_in[0];
  const float* r       = (const float*)d_in[1];
  const float* mems    = (const float*)d_in[2];
  const float* qkv_w   = (const float*)d_in[3];
  const float* r_net_w = (const float*)d_in[4];
  const float* o_w     = (const float*)d_in[5];
  const float* r_w_bias= (const float*)d_in[6];
  const float* r_r_bias= (const float*)d_in[7];
  const float* ln1_g   = (const float*)d_in[8];
  const float* ln1_b   = (const float*)d_in[9];
  const float* ff_w1   = (const float*)d_in[10];
  const float* ff_b1   = (const float*)d_in[11];
  const float* ff_w2   = (const float*)d_in[12];
  const float* ff_b2   = (const float*)d_in[13];
  const float* ln2_g   = (const float*)d_in[14];
  const float* ln2_b   = (const float*)d_in[15];
  float* out = (float*)d_out;

  // ---- workspace carve-up ----
  float* X1 = (float*)d_ws;                               // 4,194,304 f32
  unsigned short* Qh   = (unsigned short*)(X1 + 4194304); // 4,194,304 bf16
  unsigned short* Kh   = Qh + 4194304;                    // 8,388,608
  unsigned short* Vt   = Kh + 8388608;                    // 8,388,608
  unsigned short* Rk   = Vt + 8388608;                    // 2,097,152 (+8192 pad)
  unsigned short* Xcat = Rk + 2097152 + 8192;             // 8,388,608
  unsigned short* Wqkv = Xcat + 8388608;                  // 3,145,728
  unsigned short* Wr   = Wqkv + 3145728;                  // 1,048,576
  unsigned short* Wo   = Wr + 1048576;                    // 1,048,576
  unsigned short* W1   = Wo + 1048576;                    // 4,194,304
  unsigned short* W2   = W1 + 4194304;                    // 4,194,304
  float* den0 = (float*)(W2 + 4194304);                   // 65,536 f32
  float* den1 = den0 + 65536;                             // 65,536 f32
  unsigned short* AVb  = (unsigned short*)(den1 + 65536); // 4,194,304 bf16
  // aliases (disjoint lifetimes):
  unsigned short* Vh     = (unsigned short*)X1;  // qkv V (dead after transpose_v)
  unsigned short* Rb16   = AVb;                  // r bf16 (dead after rproj)
  float* Opart0          = (float*)X1;           // attn partial, split 0 (16MB)
  float* Opart1          = (float*)Xcat;         // attn partial, split 1 (16MB)
  unsigned short* X1b    = Qh;                   // ln1 bf16 (Qh dead after attn)
  unsigned short* H      = Kh;                   // ffn hidden (spans Kh+Vt)

  const dim3 blk(256);
  const dim3 blk2(512);

  // prep: 2 launches
  cast_all<<<dim3(5120), blk, 0, stream>>>(mems, w, r, Xcat, Rb16);
  transpose_all<<<dim3(3328), blk, 0, stream>>>(
      qkv_w, r_net_w, o_w, ff_w1, ff_w2, Wqkv, Wr, Wo, W1, W2);

  // 1. QKV fused -> Qh/Kh bf16, Vh row-major (256^2); then V transpose
  mgemm2<0><<<dim3(12, 32), blk2, 0, stream>>>(
      Xcat, Wqkv, Qh, nullptr, Kh, Vh, DMODEL, 3 * DMODEL);
  transpose_v<<<dim3(32, 64), blk, 0, stream>>>(Vh, Vt);
  // 2. R projection -> Rk bf16 (128x128 tile, 128 blocks)
  mgemm<1, 128><<<dim3(8, 16), blk, 0, stream>>>(
      Rb16, Wr, nullptr, Rk, nullptr, nullptr, DMODEL, DMODEL);
  // 3. MFMA flash attention (j-split) -> fp32 partials; combine -> AVb bf16
  attn_mfma<<<dim3(32, 64), blk, 0, stream>>>(
      Qh, Kh, Vt, Rk, r_w_bias, r_r_bias, Opart0, Opart1, den0, den1);
  attn_combine<<<dim3(1024), blk, 0, stream>>>(Opart0, Opart1, den0, den1, AVb);
  // 4. o-proj + residual -> X1 fp32 (128x128, 256 blocks); LN1 (+X1b bf16)
  mgemm<2, 128><<<dim3(8, 32), blk, 0, stream>>>(
      AVb, Wo, X1, nullptr, nullptr, w, DMODEL, DMODEL);
  ln_kernel<<<dim3(4096), blk, 0, stream>>>(X1, ln1_g, ln1_b, X1b);
  // 5. FFN up + relu -> H bf16 (256^2 kernel)
  mgemm2<3><<<dim3(16, 16), blk2, 0, stream>>>(
      X1b, W1, H, ff_b1, nullptr, nullptr, DMODEL, DINNER);
  // 6. FFN down + bias + residual -> out fp32 (128x128, 256 blocks); LN2
  mgemm<4, 128><<<dim3(8, 32), blk, 0, stream>>>(
      H, W2, out, nullptr, ff_b2, X1, DINNER, DMODEL);
  ln_kernel<<<dim3(4096), blk, 0, stream>>>(out, ln2_g, ln2_b, nullptr);

  (void)in_sizes; (void)n_in; (void)out_size; (void)ws_size;
}

// Round 11
// 502.009 us; speedup vs baseline: 1.0519x; 1.0377x over previous
//
#include <hip/hip_runtime.h>
#include <math.h>

// ---------------------------------------------------------------------------
// MemTransformerLM (Transformer-XL layer) — round 17.
// attn: i-tile 128 / 8 waves (512 thr). Per-wave code identical to r14; chunk
//   count and barrier events halve (25088->12800), K/V staging bytes halve.
//   LDS 80KB: K dbuf 2x8K | V dbuf 2x8K | R-ring 256 rows (32K, phys=&255) |
//   Ps 16K. 2x81920 = 163840 = exact CU LDS -> 2 blocks/CU (4 waves/SIMD).
//   R invariant row = 1023+dj: band tiles (7-wv+s), gw = j0-i0+896; Rk pad
//   extended to 128 rows (max touched row 2175).
// GEMMs: r16 config unchanged (ledger: 7 structural variants all neutral).
// ---------------------------------------------------------------------------

#define QLEN 1024
#define BSZ  4
#define DMODEL 1024
#define NHEAD 16
#define DHEAD 64
#define DINNER 4096
#define MEMLEN 1024
#define KLEN 2048

typedef __attribute__((ext_vector_type(8))) short short8;
typedef __attribute__((ext_vector_type(4))) short short4_t;
typedef __attribute__((ext_vector_type(4))) float f32x4;

__device__ __forceinline__ unsigned short f2bf(float x) {
  union { float f; unsigned u; } cv; cv.f = x;
  const unsigned u = cv.u;
  return (unsigned short)((u + 0x7FFFu + ((u >> 16) & 1u)) >> 16);
}
__device__ __forceinline__ float bf2f(unsigned short b) {
  union { unsigned u; float f; } cv; cv.u = ((unsigned)b) << 16;
  return cv.f;
}

__device__ __forceinline__ void gload16(const void* g, void* l) {
  __builtin_amdgcn_global_load_lds(
      (const __attribute__((address_space(1))) unsigned int*)g,
      (__attribute__((address_space(3))) unsigned int*)l, 16, 0, 0);
}

__device__ __forceinline__ int chidx(int row, int kc) {
  return row * 4 + (kc ^ ((row >> 1) & 3));
}

// ---------------------------------------------------------------------------
// mgemm2: C[M,N] = A[M,K] @ Bt[N,K]^T, 256x256 tile, BK=32, 512 threads.
// Depth-2 pipeline, 96KB LDS (3 bufs), vmcnt(8/4/0) ladder. 2 barriers/tile.
// MODE 0: QKV fused (sec 0=Q guarded, 1=K, 2=V). MODE 3: FFN up+bias+relu.
// Epilogue: LDS-staged vectorized C-store (wave-private 8KB regions).
// ---------------------------------------------------------------------------
template<int MODE>
__global__ __launch_bounds__(512) void mgemm2(
    const unsigned short* __restrict__ A, const unsigned short* __restrict__ Bt,
    unsigned short* __restrict__ Cb, const float* __restrict__ aux,
    unsigned short* __restrict__ oK, unsigned short* __restrict__ oV,
    int Kdim, int N)
{
  __shared__ __align__(16) char smem[98304];

  const int tid = threadIdx.x;
  const int lane = tid & 63, wv = tid >> 6;
  const int wr = wv >> 2, wc = wv & 3;
  const int quad = lane >> 4, l15 = lane & 15;

  const int gx = (int)gridDim.x;
  const int nwg = gx * (int)gridDim.y;
  const int flat = (int)blockIdx.y * gx + (int)blockIdx.x;
  const int swz = (flat & 7) * (nwg >> 3) + (flat >> 3);
  const int m0 = (swz / gx) * 256, n0 = (swz % gx) * 256;

  const int srow = tid >> 2;
  const int skc = (tid & 3) ^ ((srow >> 1) & 3);
  const unsigned short* pA0 = A + (size_t)(m0 + srow) * Kdim + skc * 8;
  const unsigned short* pA1 = A + (size_t)(m0 + 128 + srow) * Kdim + skc * 8;
  const unsigned short* pB0 = Bt + (size_t)(n0 + srow) * Kdim + skc * 8;
  const unsigned short* pB1 = Bt + (size_t)(n0 + 128 + srow) * Kdim + skc * 8;
  const int wb = (tid & 448) * 16;          // wave-uniform LDS base

  const int cch = (quad ^ ((l15 >> 1) & 3)) * 16;
  const int aoffb = wr * 8192 + l15 * 64 + cch;                      // +i*1024
  const int boffb = (wc >> 1) * 8192 + ((wc & 1) * 64 + l15) * 64 + cch;

  f32x4 acc[8][4] = {};

  const int nkt = Kdim >> 5;
  // prologue: stage kt=0 -> buf0, kt=1 -> buf1 (8 loads outstanding)
  gload16(pA0, smem + wb);
  gload16(pA1, smem + 8192 + wb);
  gload16(pB0, smem + 49152 + wb);
  gload16(pB1, smem + 57344 + wb);
  pA0 += 32; pA1 += 32; pB0 += 32; pB1 += 32;
  gload16(pA0, smem + 16384 + wb);
  gload16(pA1, smem + 24576 + wb);
  gload16(pB0, smem + 65536 + wb);
  gload16(pB1, smem + 73728 + wb);
  pA0 += 32; pA1 += 32; pB0 += 32; pB1 += 32;

  int rbuf = 0;
  for (int kt = 0; kt < nkt; ++kt) {
    if (kt + 2 < nkt) {
      int wb3 = rbuf + 2; if (wb3 >= 3) wb3 -= 3;
      const int ab = wb3 * 16384, bb = 49152 + wb3 * 16384;
      gload16(pA0, smem + ab + wb);
      gload16(pA1, smem + ab + 8192 + wb);
      gload16(pB0, smem + bb + wb);
      gload16(pB1, smem + bb + 8192 + wb);
      pA0 += 32; pA1 += 32; pB0 += 32; pB1 += 32;
      asm volatile("s_waitcnt vmcnt(8)" ::: "memory");
    } else if (kt + 1 < nkt) {
      asm volatile("s_waitcnt vmcnt(4)" ::: "memory");
    } else {
      asm volatile("s_waitcnt vmcnt(0)" ::: "memory");
    }
    __builtin_amdgcn_s_barrier();            // A: buf rbuf staged & visible

    const char* const abuf = smem + rbuf * 16384;
    const char* const bbuf = smem + 49152 + rbuf * 16384;

    // ---- phase 0: B all + A rows 0..63 ----
    short8 bfr[4], af[4];
#pragma unroll
    for (int j = 0; j < 4; ++j)
      bfr[j] = *(const short8*)(bbuf + boffb + j * 1024);
#pragma unroll
    for (int i = 0; i < 4; ++i)
      af[i] = *(const short8*)(abuf + aoffb + i * 1024);
    __builtin_amdgcn_s_setprio(1);
#pragma unroll
    for (int i = 0; i < 4; ++i)
#pragma unroll
      for (int j = 0; j < 4; ++j)
        acc[i][j] = __builtin_amdgcn_mfma_f32_16x16x32_bf16(
            af[i], bfr[j], acc[i][j], 0, 0, 0);
    __builtin_amdgcn_s_setprio(0);

    // ---- phase 1: A rows 64..127 (same staged buffer; no barrier needed) ----
#pragma unroll
    for (int i = 0; i < 4; ++i)
      af[i] = *(const short8*)(abuf + aoffb + (i + 4) * 1024);
    __builtin_amdgcn_s_setprio(1);
#pragma unroll
    for (int i = 0; i < 4; ++i)
#pragma unroll
      for (int j = 0; j < 4; ++j)
        acc[i + 4][j] = __builtin_amdgcn_mfma_f32_16x16x32_bf16(
            af[i], bfr[j], acc[i + 4][j], 0, 0, 0);
    __builtin_amdgcn_s_setprio(0);
    asm volatile("s_waitcnt lgkmcnt(0)" ::: "memory");
    __builtin_amdgcn_s_barrier();            // E: all reads of buf rbuf done
    rbuf += 1; if (rbuf == 3) rbuf = 0;
  }

  // ---- epilogue: LDS-staged vectorized C-store ----
  const int cbw = n0 + wc * 64;              // wave-uniform col base
  float bias[4];
  if constexpr (MODE == 3) {
#pragma unroll
    for (int j = 0; j < 4; ++j) bias[j] = aux[cbw + j * 16 + l15];
  }
  unsigned short* const eb = (unsigned short*)(smem + wv * 8192);
  for (int half = 0; half < 2; ++half) {
#pragma unroll
    for (int ii = 0; ii < 4; ++ii) {
#pragma unroll
      for (int r = 0; r < 4; ++r) {
        const int lr = ii * 16 + quad * 4 + r;
#pragma unroll
        for (int j = 0; j < 4; ++j) {
          float v = acc[half * 4 + ii][j][r];
          if constexpr (MODE == 3) v = fmaxf(v + bias[j], 0.f);
          const int slot = (j * 2 + (l15 >> 3)) ^ (lr & 7);
          eb[lr * 64 + slot * 8 + (l15 & 7)] = f2bf(v);
        }
      }
    }
    const int grow = m0 + wr * 128 + half * 64 + lane;
    short8 row[8];
#pragma unroll
    for (int g = 0; g < 8; ++g)
      row[g] = *(const short8*)(eb + lane * 64 + ((g ^ (lane & 7)) * 8));
    if constexpr (MODE == 0) {               // QKV: sec 0=Q(guarded) 1=K 2=V
      const int kkg = grow >> 2, b2 = grow & 3;
      const int sec = cbw >> 10, hn = (cbw >> 6) & 15;
      unsigned short* dst = nullptr;
      bool doit = true;
      if (sec == 0) {
        doit = (kkg >= MEMLEN);
        dst = Cb + ((size_t)(b2 * NHEAD + hn) * QLEN + (kkg - MEMLEN)) * DHEAD;
      } else if (sec == 1) {
        dst = oK + ((size_t)(b2 * NHEAD + hn) * KLEN + kkg) * DHEAD;
      } else {
        dst = oV + ((size_t)(b2 * NHEAD + hn) * KLEN + kkg) * DHEAD;
      }
      if (doit) {
#pragma unroll
        for (int g = 0; g < 8; ++g) *(short8*)(dst + g * 8) = row[g];
      }
    } else {
      unsigned short* dst = Cb + (size_t)grow * N + cbw;
#pragma unroll
      for (int g = 0; g < 8; ++g) *(short8*)(dst + g * 8) = row[g];
    }
  }
}

// ---------------------------------------------------------------------------
// bf16 MFMA GEMM: 128xTN tile, BK=32, 4 waves, depth-2 (3 bufs). (r16 form)
// ---------------------------------------------------------------------------
template<int MODE, int TN>
__global__ __launch_bounds__(256) void mgemm(
    const unsigned short* __restrict__ A, const unsigned short* __restrict__ Bt,
    float* __restrict__ C, unsigned short* __restrict__ Cb,
    const float* __restrict__ aux, const float* __restrict__ res,
    int Kdim, int N)
{
  constexpr int BUF = 8192 + TN * 64;          // bytes per stage buffer
  __shared__ __align__(16) char smem[3 * BUF];

  const int tid = threadIdx.x;
  const int lane = tid & 63, wv = tid >> 6;

  const int gx = (int)gridDim.x;
  const int nwg = gx * (int)gridDim.y;
  const int flat = (int)blockIdx.y * gx + (int)blockIdx.x;
  const int swz = (flat & 7) * (nwg >> 3) + (flat >> 3);
  const int m0 = (swz / gx) * 128, n0 = (swz % gx) * TN;

  const unsigned short *gA0, *gA1, *gB0, *gB1 = nullptr;
  {
    int c = tid, m = c >> 2, kc = (c & 3) ^ ((m >> 1) & 3);
    gA0 = A + (size_t)(m0 + m) * Kdim + kc * 8;
    c = 256 + tid; m = c >> 2; kc = (c & 3) ^ ((m >> 1) & 3);
    gA1 = A + (size_t)(m0 + m) * Kdim + kc * 8;
    c = tid; int nn = c >> 2; kc = (c & 3) ^ ((nn >> 1) & 3);
    gB0 = Bt + (size_t)(n0 + nn) * Kdim + kc * 8;
    if constexpr (TN == 128) {
      c = 256 + tid; nn = c >> 2; kc = (c & 3) ^ ((nn >> 1) & 3);
      gB1 = Bt + (size_t)(n0 + nn) * Kdim + kc * 8;
    }
  }
  const int wvoff = (tid & 192) * 16;

  const int fr = lane & 15, kq = lane >> 4;
  constexpr int NJ = TN / 32;
  int aoff[4], boff[NJ];
#pragma unroll
  for (int t = 0; t < 4; ++t) {
    const int ra = (wv & 1) * 64 + t * 16 + fr;
    aoff[t] = chidx(ra, kq) * 16;
  }
#pragma unroll
  for (int t = 0; t < NJ; ++t) {
    const int rb = (wv >> 1) * (TN / 2) + t * 16 + fr;
    boff[t] = 8192 + chidx(rb, kq) * 16;
  }

  f32x4 acc[4][NJ] = {};

  // prologue: stage step 0 -> buf0, step 1 -> buf1
  {
    char* const b0 = smem + wvoff;
    gload16(gA0, b0);
    gload16(gA1, b0 + 4096);
    gload16(gB0, b0 + 8192);
    if constexpr (TN == 128) gload16(gB1, b0 + 12288);
    gA0 += 32; gA1 += 32; gB0 += 32;
    if constexpr (TN == 128) gB1 += 32;
    char* const b1 = smem + BUF + wvoff;
    gload16(gA0, b1);
    gload16(gA1, b1 + 4096);
    gload16(gB0, b1 + 8192);
    if constexpr (TN == 128) gload16(gB1, b1 + 12288);
    gA0 += 32; gA1 += 32; gB0 += 32;
    if constexpr (TN == 128) gB1 += 32;
  }

  int rbuf = 0;
  for (int k0 = 0; k0 < Kdim; k0 += 32) {
    if (k0 + 64 < Kdim) {
      int wb3 = rbuf + 2; if (wb3 >= 3) wb3 -= 3;
      char* const nb = smem + wb3 * BUF + wvoff;
      gload16(gA0, nb);
      gload16(gA1, nb + 4096);
      gload16(gB0, nb + 8192);
      if constexpr (TN == 128) gload16(gB1, nb + 12288);
      gA0 += 32; gA1 += 32; gB0 += 32;
      if constexpr (TN == 128) gB1 += 32;
      if constexpr (TN == 128)
        asm volatile("s_waitcnt vmcnt(8)" ::: "memory");
      else
        asm volatile("s_waitcnt vmcnt(6)" ::: "memory");
    } else if (k0 + 32 < Kdim) {
      if constexpr (TN == 128)
        asm volatile("s_waitcnt vmcnt(4)" ::: "memory");
      else
        asm volatile("s_waitcnt vmcnt(3)" ::: "memory");
    } else {
      asm volatile("s_waitcnt vmcnt(0)" ::: "memory");
    }
    __builtin_amdgcn_s_barrier();          // buffer `rbuf` fully staged

    const char* const cb = smem + rbuf * BUF;
    short8 af[4], bfr[NJ];
#pragma unroll
    for (int t = 0; t < 4; ++t) af[t] = *(const short8*)(cb + aoff[t]);
#pragma unroll
    for (int t = 0; t < NJ; ++t) bfr[t] = *(const short8*)(cb + boff[t]);
#pragma unroll
    for (int i = 0; i < 4; ++i)
#pragma unroll
      for (int j = 0; j < NJ; ++j)
        acc[i][j] = __builtin_amdgcn_mfma_f32_16x16x32_bf16(
            af[i], bfr[j], acc[i][j], 0, 0, 0);

    asm volatile("s_waitcnt lgkmcnt(0)" ::: "memory");
    __builtin_amdgcn_s_barrier();          // all reads of `rbuf` done
    rbuf += 1; if (rbuf == 3) rbuf = 0;
  }

  const int rbase = m0 + (wv & 1) * 64 + (lane >> 4) * 4;
  const int cbase = n0 + (wv >> 1) * (TN / 2) + (lane & 15);
#pragma unroll
  for (int i = 0; i < 4; ++i) {
#pragma unroll
    for (int r = 0; r < 4; ++r) {
      const int grow = rbase + i * 16 + r;
#pragma unroll
      for (int j = 0; j < NJ; ++j) {
        const int gcol = cbase + j * 16;
        const float v = acc[i][j][r];
        if constexpr (MODE == 1) {
          const int hn = gcol >> 6, d = gcol & 63;
          Cb[((size_t)hn * KLEN + grow) * DHEAD + d] = f2bf(v);
        } else if constexpr (MODE == 2) {
          C[(size_t)grow * N + gcol] = v + res[(size_t)grow * N + gcol];
        } else {
          C[(size_t)grow * N + gcol] = v + aux[gcol] + res[(size_t)grow * N + gcol];
        }
      }
    }
  }
}

// ---------------------------------------------------------------------------
// Vh [bn][j][d] bf16 -> Vt [bn][d][j] bf16.
// ---------------------------------------------------------------------------
__global__ __launch_bounds__(256) void transpose_v(
    const unsigned short* __restrict__ Vh, unsigned short* __restrict__ Vt)
{
  __shared__ unsigned short t[64 * 80];
  const int j0 = (int)blockIdx.x * 64;
  const int bn = (int)blockIdx.y;
  const int tid = threadIdx.x;
#pragma unroll
  for (int it = 0; it < 2; ++it) {
    const int f = it * 256 + tid;
    const int j = f >> 3, d8 = (f & 7) * 8;
    const short8 v = *(const short8*)(Vh + ((size_t)bn * KLEN + j0 + j) * DHEAD + d8);
    *(short8*)(t + j * 80 + d8) = v;
  }
  __syncthreads();
  const int d = tid >> 2, jseg = (tid & 3) * 16;
  short8 o0, o1;
#pragma unroll
  for (int e = 0; e < 8; ++e) o0[e] = (short)t[(jseg + e) * 80 + d];
#pragma unroll
  for (int e = 0; e < 8; ++e) o1[e] = (short)t[(jseg + 8 + e) * 80 + d];
  unsigned short* op = Vt + ((size_t)bn * DHEAD + d) * KLEN + j0 + jseg;
  *(short8*)op = o0;
  *(short8*)(op + 8) = o1;
}

// ---------------------------------------------------------------------------
// merged input casts: mems|w -> Xcat, r -> Rb16. grid 5120.
// ---------------------------------------------------------------------------
__global__ __launch_bounds__(256) void cast_all(
    const float* __restrict__ mems, const float* __restrict__ w,
    const float* __restrict__ r, unsigned short* __restrict__ Xcat,
    unsigned short* __restrict__ Rb16)
{
  const size_t i = ((size_t)blockIdx.x * 256 + threadIdx.x) * 8;
  const float* src;
  unsigned short* dst;
  if (i < 4194304)       { src = mems + i;          dst = Xcat + i; }
  else if (i < 8388608)  { src = w + (i - 4194304); dst = Xcat + i; }
  else                   { src = r + (i - 8388608); dst = Rb16 + (i - 8388608); }
  const float4 x = *(const float4*)src;
  const float4 y = *(const float4*)(src + 4);
  short8 v;
  v[0] = (short)f2bf(x.x); v[1] = (short)f2bf(x.y);
  v[2] = (short)f2bf(x.z); v[3] = (short)f2bf(x.w);
  v[4] = (short)f2bf(y.x); v[5] = (short)f2bf(y.y);
  v[6] = (short)f2bf(y.z); v[7] = (short)f2bf(y.w);
  *(short8*)dst = v;
}

// ---------------------------------------------------------------------------
// merged weight transposes: fp32 [R][C] -> bf16 [C][R], 5 weights. grid 3328.
// ---------------------------------------------------------------------------
__global__ __launch_bounds__(256) void transpose_all(
    const float* __restrict__ qkv_w, const float* __restrict__ r_net_w,
    const float* __restrict__ o_w, const float* __restrict__ ff_w1,
    const float* __restrict__ ff_w2,
    unsigned short* __restrict__ Wqkv, unsigned short* __restrict__ Wr,
    unsigned short* __restrict__ Wo, unsigned short* __restrict__ W1,
    unsigned short* __restrict__ W2)
{
  const int bid = (int)blockIdx.x;
  const float* in; unsigned short* out; int R, C, xt, loc;
  if (bid < 768)        { in = qkv_w;   out = Wqkv; R = 1024; C = 3072; xt = 48; loc = bid; }
  else if (bid < 1024)  { in = r_net_w; out = Wr;   R = 1024; C = 1024; xt = 16; loc = bid - 768; }
  else if (bid < 1280)  { in = o_w;     out = Wo;   R = 1024; C = 1024; xt = 16; loc = bid - 1024; }
  else if (bid < 2304)  { in = ff_w1;   out = W1;   R = 1024; C = 4096; xt = 64; loc = bid - 1280; }
  else                  { in = ff_w2;   out = W2;   R = 4096; C = 1024; xt = 16; loc = bid - 2304; }
  const int c0 = (loc % xt) * 64, r0 = (loc / xt) * 64;

  __shared__ float t[64][65];
  const int tid = threadIdx.x;
  const int rr = tid >> 4, cc = (tid & 15) * 4;
#pragma unroll
  for (int it = 0; it < 4; ++it) {
    const int rw = rr + it * 16;
    const float4 v = *(const float4*)(in + (size_t)(r0 + rw) * C + c0 + cc);
    t[rw][cc] = v.x; t[rw][cc + 1] = v.y; t[rw][cc + 2] = v.z; t[rw][cc + 3] = v.w;
  }
  __syncthreads();
  const int oc = tid >> 2, ob = (tid & 3) * 16;
#pragma unroll
  for (int j4 = 0; j4 < 4; ++j4) {
    short4_t o;
#pragma unroll
    for (int j = 0; j < 4; ++j) o[j] = (short)f2bf(t[ob + j4 * 4 + j][oc]);
    *(short4_t*)(out + (size_t)(c0 + oc) * R + r0 + ob + j4 * 4) = o;
  }
}

// ---------------------------------------------------------------------------
// MFMA flash relative attention, r17: i-tile 128, 8 waves (512 thr).
// grid 1024 flattened + XCD swizzle; j-split 2 (sp).
// LDS 80KB: K dbuf 2x8K @0 | V dbuf 2x8K @16K | R-ring 256 rows (32K) @32768 |
//           Ps 16K @65536 (wave-private rows).
// R invariant: global row = 1023 + (j-i); window/chunk = 192 rows starting at
// gw = j0-i0+896; ring phys = row & 255; prefetch writes [gw+192,gw+256).
// Per chunk: 3 gload_lds (K,V,R) prefetch; counted vmcnt(3); 2 barriers.
// ---------------------------------------------------------------------------
__global__ __launch_bounds__(512, 4) void attn_mfma(
    const unsigned short* __restrict__ Qh, const unsigned short* __restrict__ Kh,
    const unsigned short* __restrict__ Vt, const unsigned short* __restrict__ Rk,
    const float* __restrict__ rwb, const float* __restrict__ rrb,
    float* __restrict__ Opart0, float* __restrict__ Opart1,
    float* __restrict__ den0, float* __restrict__ den1)
{
  __shared__ __align__(16) char smem[81920];

  const int tid = threadIdx.x;
  const int lane = tid & 63, wv = tid >> 6;          // wv in 0..7
  const int quad = lane >> 4, l15 = lane & 15;

  const int bid0 = (int)blockIdx.y * 32 + (int)blockIdx.x;   // 0..1023
  const int slot = bid0 >> 3;
  const int bn = (bid0 & 7) * 8 + (slot >> 4);               // XCD-chunked
  const int inner = slot & 15;
  const int it = inner >> 1, sp = inner & 1;                 // it 0..7
  const int i0 = it * 128;
  const int n = bn & 15;

  const int nch = 18 + 2 * it;
  const int h = 9 + it;
  const int lo = sp ? h : 0, hi = sp ? nch : h;

  const unsigned short* __restrict__ Qb = Qh + (size_t)bn * QLEN * DHEAD;
  const unsigned short* __restrict__ Kb = Kh + (size_t)bn * KLEN * DHEAD;
  const unsigned short* __restrict__ Vb = Vt + (size_t)bn * DHEAD * KLEN;
  const unsigned short* __restrict__ Rb = Rk + (size_t)n * KLEN * DHEAD;

  // persistent Q fragments with biases folded (wave owns i-rows wv*16..+16)
  short8 qk[2], qr[2];
  {
    const int qrow = i0 + wv * 16 + l15;
    const unsigned short* qp = Qb + (size_t)qrow * DHEAD + quad * 8;
    const float* wp = rwb + n * DHEAD + quad * 8;
    const float* rp = rrb + n * DHEAD + quad * 8;
#pragma unroll
    for (int ks = 0; ks < 2; ++ks) {
      const short8 q8 = *(const short8*)(qp + ks * 32);
#pragma unroll
      for (int e = 0; e < 8; ++e) {
        const float qv = bf2f((unsigned short)q8[e]);
        qk[ks][e] = (short)f2bf(qv + wp[ks * 32 + e]);
        qr[ks][e] = (short)f2bf(qv + rp[ks * 32 + e]);
      }
    }
  }

  // bpermute lane maps + selectors (per register r)
  int srcl[4];
  bool condE[4];
#pragma unroll
  for (int r = 0; r < 4; ++r) {
    const int E = l15 - quad * 4 - r + 15;           // in [0,30]
    srcl[r] = (lane & 48) | (E & 15);
    condE[r] = (E >= 16);
  }

  f32x4 O[4] = {};
  float rden[4] = {0.f, 0.f, 0.f, 0.f};
  const int wvoff = (tid & 448) * 16;                // wv*1024
  const int srow = tid >> 3;                         // 0..63
  const int skc7 = (tid & 7) ^ (srow & 7);

  // ---- prologue: K,V of chunk `lo` (1 load each) + R rows [gw, gw+192) ----
  {
    const int j0 = lo * 64;
    gload16(Kb + (((size_t)(j0 + srow)) << 6) + skc7 * 8, smem + wvoff);
    gload16(Vb + (((size_t)srow) << 11) + j0 + skc7 * 8, smem + 16384 + wvoff);
    const int gw = j0 - i0 + 896;
#pragma unroll
    for (int t2 = 0; t2 < 3; ++t2) {
      const int gr = gw + t2 * 64 + srow;
      const int brow = (gw + t2 * 64 + ((tid & 448) >> 3)) & 255;  // wave-unif
      gload16(Rb + (((size_t)gr) << 6) + skc7 * 8,
              smem + 32768 + brow * 128);
    }
  }

  int cur = 0;
  for (int ch = lo; ch < hi; ++ch) {
    const int j0 = ch * 64;
    const int gw = j0 - i0 + 896;

    asm volatile("s_waitcnt lgkmcnt(0)" ::: "memory");
    __builtin_amdgcn_s_barrier();                    // A: prior reads done

    if (ch + 1 < hi) {
      // prefetch chunk ch+1: K,V into buf cur^1; R rows [gw+192, gw+256)
      const int nb = cur ^ 1;
      const int j0n = j0 + 64;
      gload16(Kb + (((size_t)(j0n + srow)) << 6) + skc7 * 8,
              smem + nb * 8192 + wvoff);
      gload16(Vb + (((size_t)srow) << 11) + j0n + skc7 * 8,
              smem + 16384 + nb * 8192 + wvoff);
      const int gr = gw + 192 + srow;                // pad covers rows <=2175
      const int brow = (gw + 192 + ((tid & 448) >> 3)) & 255;
      gload16(Rb + (((size_t)gr) << 6) + skc7 * 8,
              smem + 32768 + brow * 128);
      asm volatile("s_waitcnt vmcnt(3)" ::: "memory");   // ch's loads landed
    } else {
      asm volatile("s_waitcnt vmcnt(0)" ::: "memory");
    }
    __builtin_amdgcn_s_barrier();                    // B: chunk ch visible

    const char* const kbase = smem + cur * 8192;
    const char* const vbase = smem + 16384 + cur * 8192;

    // ---- S_K = (q+rwb)·k ----
    f32x4 sk[4];
#pragma unroll
    for (int jt = 0; jt < 4; ++jt) {
      f32x4 a = {0.f, 0.f, 0.f, 0.f};
#pragma unroll
      for (int ks = 0; ks < 2; ++ks) {
        const int frr = jt * 16 + l15;
        const int c = (ks * 4 + quad) ^ (l15 & 7);
        const short8 kf = *(const short8*)(kbase + (frr * 8 + c) * 16);
        a = __builtin_amdgcn_mfma_f32_16x16x32_bf16(qk[ks], kf, a, 0, 0, 0);
      }
      sk[jt] = a;
    }
    // ---- U = (q+rrb)·r band: 5 tiles (window-relative tiles 7-wv+s) ----
    const int rb256 = gw & 255;
    f32x4 uu[5];
#pragma unroll
    for (int s = 0; s < 5; ++s) {
      f32x4 a = {0.f, 0.f, 0.f, 0.f};
      const int frr = (rb256 + (7 - wv + s) * 16 + l15) & 255;   // phys row
#pragma unroll
      for (int ks = 0; ks < 2; ++ks) {
        const int c = (ks * 4 + quad) ^ (l15 & 7);
        const short8 rf = *(const short8*)(smem + 32768 + (frr * 8 + c) * 16);
        a = __builtin_amdgcn_mfma_f32_16x16x32_bf16(qr[ks], rf, a, 0, 0, 0);
      }
      uu[s] = a;
    }

    // ---- band rotate via bpermute: rot[s][r] = uu[s][r] from lane srcl[r] ----
    float rot[5][4];
#pragma unroll
    for (int s = 0; s < 5; ++s)
#pragma unroll
      for (int r = 0; r < 4; ++r)
        rot[s][r] = __shfl(uu[s][r], srcl[r], 64);

    // ---- P = exp((S_K + U)/8), masked (branchless); Ps wave-private ----
    unsigned short* const Ps = (unsigned short*)(smem + 65536);
#pragma unroll
    for (int jt = 0; jt < 4; ++jt) {
      const int jl = jt * 16 + l15;
#pragma unroll
      for (int r = 0; r < 4; ++r) {
        const int il = wv * 16 + quad * 4 + r;       // 0..127
        const int dj = (j0 + jl) - (i0 + il);
        const float uv = condE[r] ? rot[jt + 1][r] : rot[jt][r];
        const float sv = (sk[jt][r] + uv) * 0.125f;
        const float p = (dj <= 1024) ? __expf(sv) : 0.f;
        rden[r] += p;
        Ps[(il * 8 + ((jl >> 3) ^ (il & 7))) * 8 + (jl & 7)] = f2bf(p);
      }
    }

    // ---- O += P @ V (wave-private P strip) ----
#pragma unroll
    for (int ks = 0; ks < 2; ++ks) {
      const int frp = wv * 16 + l15;
      const int cp = (ks * 4 + quad) ^ (l15 & 7);
      const short8 pf = *(const short8*)(smem + 65536 + (frp * 8 + cp) * 16);
#pragma unroll
      for (int dt = 0; dt < 4; ++dt) {
        const int vr = dt * 16 + l15;
        const short8 vf = *(const short8*)(vbase + (vr * 8 + cp) * 16);
        O[dt] = __builtin_amdgcn_mfma_f32_16x16x32_bf16(pf, vf, O[dt], 0, 0, 0);
      }
    }
    cur ^= 1;
  }

  // denominator: reduce across the 16 lanes of each quad-row group
#pragma unroll
  for (int m = 1; m < 16; m <<= 1)
#pragma unroll
    for (int r = 0; r < 4; ++r)
      rden[r] += __shfl_xor(rden[r], m, 64);

  // write unnormalized fp32 partials + denominators
  // linear row index = bn*1024 + i0 + il  (same layout as before)
  float* const Op = sp ? Opart1 : Opart0;
  float* const dp = sp ? den1 : den0;
  const size_t ob = ((size_t)bn * 8 + it) * 128;
#pragma unroll
  for (int r = 0; r < 4; ++r) {
    const int il = wv * 16 + quad * 4 + r;
#pragma unroll
    for (int dt = 0; dt < 4; ++dt)
      Op[(ob + il) * 64 + dt * 16 + l15] = O[dt][r];
    if (l15 == 0) dp[ob + il] = rden[r];
  }
}

// ---------------------------------------------------------------------------
// combine j-split partials: AVb = bf16((O0+O1) / (d0+d1)). grid 1024.
// (row layout is linear in bn*1024 + q-row — unchanged by the attn regroup)
// ---------------------------------------------------------------------------
__global__ __launch_bounds__(256) void attn_combine(
    const float* __restrict__ O0, const float* __restrict__ O1,
    const float* __restrict__ d0, const float* __restrict__ d1,
    unsigned short* __restrict__ AVb)
{
  const int blk = (int)blockIdx.x;           // bn*16 + it64
  const int bn = blk >> 4, it = blk & 15;
  const int b = bn >> 4, n = bn & 15;
  const int tid = threadIdx.x;
  const int il = tid >> 2, ds = (tid & 3) * 16;
  const size_t base = ((size_t)blk * 64 + il) * 64 + ds;
  const float inv = 1.f / (d0[blk * 64 + il] + d1[blk * 64 + il]);
  short8 o0, o1;
#pragma unroll
  for (int g = 0; g < 2; ++g) {
    const float4 a = *(const float4*)(O0 + base + g * 8);
    const float4 bb = *(const float4*)(O1 + base + g * 8);
    const float4 a2 = *(const float4*)(O0 + base + g * 8 + 4);
    const float4 b2 = *(const float4*)(O1 + base + g * 8 + 4);
    short8& o = g ? o1 : o0;
    o[0] = (short)f2bf((a.x + bb.x) * inv);  o[1] = (short)f2bf((a.y + bb.y) * inv);
    o[2] = (short)f2bf((a.z + bb.z) * inv);  o[3] = (short)f2bf((a.w + bb.w) * inv);
    o[4] = (short)f2bf((a2.x + b2.x) * inv); o[5] = (short)f2bf((a2.y + b2.y) * inv);
    o[6] = (short)f2bf((a2.z + b2.z) * inv); o[7] = (short)f2bf((a2.w + b2.w) * inv);
  }
  unsigned short* op =
      AVb + ((size_t)(it * 64 + il) * BSZ + b) * DMODEL + n * DHEAD + ds;
  *(short8*)op = o0;
  *(short8*)(op + 8) = o1;
}

// ---------------------------------------------------------------------------
__global__ __launch_bounds__(256) void ln_kernel(
    float* __restrict__ X, const float* __restrict__ gw,
    const float* __restrict__ bw, unsigned short* __restrict__ bfo)
{
  const int row = blockIdx.x, tid = threadIdx.x;
  float* rp = X + (size_t)row * DMODEL;
  const float4 x = *(const float4*)(rp + tid * 4);
  float s = x.x + x.y + x.z + x.w;
  float q = x.x * x.x + x.y * x.y + x.z * x.z + x.w * x.w;
#pragma unroll
  for (int m = 1; m < 64; m <<= 1) {
    s += __shfl_xor(s, m, 64);
    q += __shfl_xor(q, m, 64);
  }
  __shared__ float ss[4], sq[4];
  if ((tid & 63) == 0) { ss[tid >> 6] = s; sq[tid >> 6] = q; }
  __syncthreads();
  s = ss[0] + ss[1] + ss[2] + ss[3];
  q = sq[0] + sq[1] + sq[2] + sq[3];
  const float mu = s * (1.f / DMODEL);
  const float var = q * (1.f / DMODEL) - mu * mu;
  const float rstd = rsqrtf(var + 1e-5f);
  const float4 g4 = *(const float4*)(gw + tid * 4);
  const float4 b4 = *(const float4*)(bw + tid * 4);
  float4 y;
  y.x = (x.x - mu) * rstd * g4.x + b4.x;
  y.y = (x.y - mu) * rstd * g4.y + b4.y;
  y.z = (x.z - mu) * rstd * g4.z + b4.z;
  y.w = (x.w - mu) * rstd * g4.w + b4.w;
  *(float4*)(rp + tid * 4) = y;
  if (bfo) {
    short4_t o;
    o[0] = (short)f2bf(y.x); o[1] = (short)f2bf(y.y);
    o[2] = (short)f2bf(y.z); o[3] = (short)f2bf(y.w);
    *(short4_t*)(bfo + (size_t)row * DMODEL + tid * 4) = o;
  }
}

// ---------------------------------------------------------------------------
extern "C" void kernel_launch(void* const* d_in, const int* in_sizes, int n_in,
                              void* d_out, int out_size, void* d_ws,
                              size_t ws_size, hipStream_t stream)
{
  const float* w       = (const float*)d_in[0];
  const float* r       = (const float*)d_in[1];
  const float* mems    = (const float*)d_in[2];
  const float* qkv_w   = (const float*)d_in[3];
  const float* r_net_w = (const float*)d_in[4];
  const float* o_w     = (const float*)d_in[5];
  const float* r_w_bias= (const float*)d_in[6];
  const float* r_r_bias= (const float*)d_in[7];
  const float* ln1_g   = (const float*)d_in[8];
  const float* ln1_b   = (const float*)d_in[9];
  const float* ff_w1   = (const float*)d_in[10];
  const float* ff_b1   = (const float*)d_in[11];
  const float* ff_w2   = (const float*)d_in[12];
  const float* ff_b2   = (const float*)d_in[13];
  const float* ln2_g   = (const float*)d_in[14];
  const float* ln2_b   = (const float*)d_in[15];
  float* out = (float*)d_out;

  // ---- workspace carve-up ----
  float* X1 = (float*)d_ws;                               // 4,194,304 f32
  unsigned short* Qh   = (unsigned short*)(X1 + 4194304); // 4,194,304 bf16
  unsigned short* Kh   = Qh + 4194304;                    // 8,388,608
  unsigned short* Vt   = Kh + 8388608;                    // 8,388,608
  unsigned short* Rk   = Vt + 8388608;                    // 2,097,152 (+16384 pad)
  unsigned short* Xcat = Rk + 2097152 + 16384;            // 8,388,608
  unsigned short* Wqkv = Xcat + 8388608;                  // 3,145,728
  unsigned short* Wr   = Wqkv + 3145728;                  // 1,048,576
  unsigned short* Wo   = Wr + 1048576;                    // 1,048,576
  unsigned short* W1   = Wo + 1048576;                    // 4,194,304
  unsigned short* W2   = W1 + 4194304;                    // 4,194,304
  float* den0 = (float*)(W2 + 4194304);                   // 65,536 f32
  float* den1 = den0 + 65536;                             // 65,536 f32
  unsigned short* AVb  = (unsigned short*)(den1 + 65536); // 4,194,304 bf16
  // aliases (disjoint lifetimes):
  unsigned short* Vh     = (unsigned short*)X1;  // qkv V (dead after transpose_v)
  unsigned short* Rb16   = AVb;                  // r bf16 (dead after rproj)
  float* Opart0          = (float*)X1;           // attn partial, split 0 (16MB)
  float* Opart1          = (float*)Xcat;         // attn partial, split 1 (16MB)
  unsigned short* X1b    = Qh;                   // ln1 bf16 (Qh dead after attn)
  unsigned short* H      = Kh;                   // ffn hidden (spans Kh+Vt)

  const dim3 blk(256);
  const dim3 blk2(512);

  // prep: 2 launches
  cast_all<<<dim3(5120), blk, 0, stream>>>(mems, w, r, Xcat, Rb16);
  transpose_all<<<dim3(3328), blk, 0, stream>>>(
      qkv_w, r_net_w, o_w, ff_w1, ff_w2, Wqkv, Wr, Wo, W1, W2);

  // 1. QKV fused -> Qh/Kh bf16, Vh row-major (256^2); then V transpose
  mgemm2<0><<<dim3(12, 32), blk2, 0, stream>>>(
      Xcat, Wqkv, Qh, nullptr, Kh, Vh, DMODEL, 3 * DMODEL);
  transpose_v<<<dim3(32, 64), blk, 0, stream>>>(Vh, Vt);
  // 2. R projection -> Rk bf16 (128x128 tile, 128 blocks)
  mgemm<1, 128><<<dim3(8, 16), blk, 0, stream>>>(
      Rb16, Wr, nullptr, Rk, nullptr, nullptr, DMODEL, DMODEL);
  // 3. MFMA flash attention (i-tile 128, 8 waves) -> fp32 partials; combine
  attn_mfma<<<dim3(32, 32), blk2, 0, stream>>>(
      Qh, Kh, Vt, Rk, r_w_bias, r_r_bias, Opart0, Opart1, den0, den1);
  attn_combine<<<dim3(1024), blk, 0, stream>>>(Opart0, Opart1, den0, den1, AVb);
  // 4. o-proj + residual -> X1 fp32 (128x128, 256 blocks); LN1 (+X1b bf16)
  mgemm<2, 128><<<dim3(8, 32), blk, 0, stream>>>(
      AVb, Wo, X1, nullptr, nullptr, w, DMODEL, DMODEL);
  ln_kernel<<<dim3(4096), blk, 0, stream>>>(X1, ln1_g, ln1_b, X1b);
  // 5. FFN up + relu -> H bf16 (256^2 kernel)
  mgemm2<3><<<dim3(16, 16), blk2, 0, stream>>>(
      X1b, W1, H, ff_b1, nullptr, nullptr, DMODEL, DINNER);
  // 6. FFN down + bias + residual -> out fp32 (128x128, 256 blocks); LN2
  mgemm<4, 128><<<dim3(8, 32), blk, 0, stream>>>(
      H, W2, out, nullptr, ff_b2, X1, DINNER, DMODEL);
  ln_kernel<<<dim3(4096), blk, 0, stream>>>(out, ln2_g, ln2_b, nullptr);

  (void)in_sizes; (void)n_in; (void)out_size; (void)ws_size;
}